// Round 2
// baseline (1081.814 us; speedup 1.0000x reference)
//
#include <hip/hip_runtime.h>
#include <hip/hip_bf16.h>

typedef __bf16 bf16x8 __attribute__((ext_vector_type(8)));
typedef float f32x4 __attribute__((ext_vector_type(4)));
typedef unsigned short u16;
typedef u16 u16x8 __attribute__((ext_vector_type(8)));

#define B_ 4
#define S_ 1024
#define D_ 1024
#define E_ 4
#define H_ 16
#define FF_ 4096
#define N_ 4096

__device__ __forceinline__ u16 f2bf(float f) {
  __hip_bfloat16 h = __float2bfloat16(f);
  return *reinterpret_cast<u16*>(&h);
}

__device__ __forceinline__ void gload_lds16(const u16* g, u16* l) {
  __builtin_amdgcn_global_load_lds(
      (const __attribute__((address_space(1))) void*)g,
      (__attribute__((address_space(3))) void*)l, 16, 0, 0);
}

// ---------------- transpose + f32->bf16 convert: dst[c][r] = src[r][c] ----------------
__global__ __launch_bounds__(256) void tcvt(const float* __restrict__ src,
                                            u16* __restrict__ dst, int R, int C) {
  __shared__ float t[32][33];
  long base = (long)blockIdx.z * R * C;
  src += base; dst += base;
  int r0 = blockIdx.y * 32, c0 = blockIdx.x * 32;
  int tx = threadIdx.x, ty = threadIdx.y;  // 32 x 8
#pragma unroll
  for (int i = 0; i < 4; i++)
    t[ty + i * 8][tx] = src[(long)(r0 + ty + i * 8) * C + c0 + tx];
  __syncthreads();
#pragma unroll
  for (int i = 0; i < 4; i++)
    dst[(long)(c0 + ty + i * 8) * R + r0 + tx] = f2bf(t[tx][ty + i * 8]);
}

// ---------------- LN + router softmax + per-expert expand ----------------
// Aout[e*stride_e + n*stride_n + d] = (scale? score[e]:1) * (hn[d]*g[e][d] + b[e][d])
__global__ __launch_bounds__(256) void ln_router_expand(
    const float* __restrict__ X, const float* __restrict__ Wr, const float* __restrict__ br,
    const float* __restrict__ g, const float* __restrict__ bb,
    float* __restrict__ score_out, u16* __restrict__ Aout,
    long stride_e, long stride_n, int scale_flag) {
  int n = blockIdx.x, t = threadIdx.x;
  int lane = t & 63, wave = t >> 6;
  const float* xr = X + (long)n * D_;
  float xv[4];
  float vals[6] = {0.f, 0.f, 0.f, 0.f, 0.f, 0.f};
#pragma unroll
  for (int i = 0; i < 4; i++) {
    int d = i * 256 + t;
    float v = xr[d];
    xv[i] = v;
    vals[0] += v;
    vals[1] += v * v;
    float4 w = reinterpret_cast<const float4*>(Wr)[d];
    vals[2] += v * w.x; vals[3] += v * w.y; vals[4] += v * w.z; vals[5] += v * w.w;
  }
#pragma unroll
  for (int o = 1; o < 64; o <<= 1) {
#pragma unroll
    for (int j = 0; j < 6; j++) vals[j] += __shfl_xor(vals[j], o, 64);
  }
  __shared__ float red[4][6];
  if (lane == 0) {
#pragma unroll
    for (int j = 0; j < 6; j++) red[wave][j] = vals[j];
  }
  __syncthreads();
  float tot[6];
#pragma unroll
  for (int j = 0; j < 6; j++) tot[j] = red[0][j] + red[1][j] + red[2][j] + red[3][j];
  float mean = tot[0] * (1.0f / D_);
  float var = tot[1] * (1.0f / D_) - mean * mean;
  float rstd = rsqrtf(var + 1e-5f);
  float lg0 = tot[2] + br[0], lg1 = tot[3] + br[1], lg2 = tot[4] + br[2], lg3 = tot[5] + br[3];
  float mx = fmaxf(fmaxf(lg0, lg1), fmaxf(lg2, lg3));
  float e0 = __expf(lg0 - mx), e1 = __expf(lg1 - mx), e2 = __expf(lg2 - mx), e3 = __expf(lg3 - mx);
  float inv = 1.0f / (e0 + e1 + e2 + e3);
  float sc[4] = {e0 * inv, e1 * inv, e2 * inv, e3 * inv};
  if (t == 0) {
    float4 s4 = make_float4(sc[0], sc[1], sc[2], sc[3]);
    *reinterpret_cast<float4*>(&score_out[(long)n * 4]) = s4;
  }
#pragma unroll
  for (int i = 0; i < 4; i++) {
    int d = i * 256 + t;
    float hn = (xv[i] - mean) * rstd;
#pragma unroll
    for (int e = 0; e < 4; e++) {
      float val = hn * g[e * D_ + d] + bb[e * D_ + d];
      if (scale_flag) val *= sc[e];
      Aout[(long)e * stride_e + (long)n * stride_n + d] = f2bf(val);
    }
  }
}

// ---------------- GEMM: C[M,N] = A[M,K](bf16) * Bt[N,K]^T(bf16), epilogue by MODE -----
// MODE 0: outb = bf16(acc + sum_e score[row][e]*bias[e*N+col])            (qkv)
// MODE 1: outf = add[row*N+col] + acc + sum_e score[row][e]*bias[e*N+col] (attn proj->y)
// MODE 2: outb = bf16(score[row*4+eidx] * gelu(acc + bias[col]))          (fc)
// MODE 3: outf[row*N+col] += acc                                          (p2 accumulate)
template <int MODE>
__global__ __launch_bounds__(256) void gemm_bt(
    const u16* __restrict__ A, const u16* __restrict__ Bt, int K, int N,
    const float* __restrict__ score, const float* __restrict__ bias,
    const float* __restrict__ add, int eidx,
    u16* __restrict__ outb, float* __restrict__ outf) {
  __shared__ __align__(16) u16 As[128 * 64];
  __shared__ __align__(16) u16 Bs[128 * 64];
  int tid = threadIdx.x;
  int wave = tid >> 6, lane = tid & 63;
  int l15 = lane & 15, l4 = lane >> 4;
  int wm = (wave >> 1) * 64, wn = (wave & 1) * 64;
  long bm = (long)blockIdx.y * 128, bn = (long)blockIdx.x * 128;

  f32x4 acc[4][4] = {};

  const u16* Ag = A + (bm + wave * 32 + (lane >> 3)) * (long)K + (lane & 7) * 8;
  const u16* Bg = Bt + (bn + wave * 32 + (lane >> 3)) * (long)K + (lane & 7) * 8;
  u16* Al = &As[wave * 32 * 64];
  u16* Bl = &Bs[wave * 32 * 64];

  for (int k0 = 0; k0 < K; k0 += 64) {
#pragma unroll
    for (int i = 0; i < 4; i++) {
      gload_lds16(Ag + (long)i * 8 * K + k0, Al + i * 8 * 64);
      gload_lds16(Bg + (long)i * 8 * K + k0, Bl + i * 8 * 64);
    }
    __syncthreads();
#pragma unroll
    for (int kc = 0; kc < 2; kc++) {
      bf16x8 af[4], bfr[4];
#pragma unroll
      for (int mi = 0; mi < 4; mi++)
        af[mi] = *(const bf16x8*)&As[(wm + mi * 16 + l15) * 64 + kc * 32 + l4 * 8];
#pragma unroll
      for (int ni = 0; ni < 4; ni++)
        bfr[ni] = *(const bf16x8*)&Bs[(wn + ni * 16 + l15) * 64 + kc * 32 + l4 * 8];
#pragma unroll
      for (int mi = 0; mi < 4; mi++) {
#pragma unroll
        for (int ni = 0; ni < 4; ni++)
          acc[mi][ni] =
              __builtin_amdgcn_mfma_f32_16x16x32_bf16(af[mi], bfr[ni], acc[mi][ni], 0, 0, 0);
      }
    }
    __syncthreads();
  }

#pragma unroll
  for (int mi = 0; mi < 4; mi++) {
    long rbase = bm + wm + mi * 16 + (l4 << 2);
    float scr[4][4];
    if (MODE == 0 || MODE == 1) {
#pragma unroll
      for (int r = 0; r < 4; r++) {
        float4 s4 = reinterpret_cast<const float4*>(score)[rbase + r];
        scr[r][0] = s4.x; scr[r][1] = s4.y; scr[r][2] = s4.z; scr[r][3] = s4.w;
      }
    } else if (MODE == 2) {
#pragma unroll
      for (int r = 0; r < 4; r++) scr[r][0] = score[(rbase + r) * 4 + eidx];
    }
#pragma unroll
    for (int ni = 0; ni < 4; ni++) {
      long col = bn + wn + ni * 16 + l15;
      float b4[4];
      if (MODE == 0 || MODE == 1) {
#pragma unroll
        for (int e = 0; e < 4; e++) b4[e] = bias[(long)e * N + col];
      }
      float bcol = (MODE == 2) ? bias[col] : 0.0f;
#pragma unroll
      for (int r = 0; r < 4; r++) {
        long row = rbase + r;
        long idx = row * (long)N + col;
        float v = acc[mi][ni][r];
        if (MODE == 0) {
          v += scr[r][0] * b4[0] + scr[r][1] * b4[1] + scr[r][2] * b4[2] + scr[r][3] * b4[3];
          outb[idx] = f2bf(v);
        } else if (MODE == 1) {
          v += add[idx] + scr[r][0] * b4[0] + scr[r][1] * b4[1] + scr[r][2] * b4[2] +
               scr[r][3] * b4[3];
          outf[idx] = v;
        } else if (MODE == 2) {
          float u = v + bcol;
          float z = 0.7978845608f * (u + 0.044715f * u * u * u);
          float t = __expf(2.0f * z);
          float gel = u * (1.0f - 1.0f / (t + 1.0f));  // 0.5u(1+tanh z), NaN-safe
          outb[idx] = f2bf(gel * scr[r][0]);
        } else {
          outf[idx] += v;
        }
      }
    }
  }
}

// ---------------- flash attention (causal), writes A_pr = score_e * attn_out --------
__global__ __launch_bounds__(256) void attn_kernel(const u16* __restrict__ qkv,
                                                   const float* __restrict__ score_a,
                                                   u16* __restrict__ A_pr) {
  __shared__ __align__(16) u16 Kt[32 * 64];   // [kv][d]
  __shared__ __align__(16) u16 VT[64 * 32];   // [d][kv]
  __shared__ __align__(16) u16 Pl[4][16 * 32];  // per-wave P [q][kv]
  int tid = threadIdx.x, wave = tid >> 6, lane = tid & 63;
  int l15 = lane & 15, l4 = lane >> 4;
  int qblk = blockIdx.x, bh = blockIdx.y;
  int b = bh >> 4, h = bh & 15;
  int q0 = qblk * 64 + wave * 16;
  const long LD = 3072;

  bf16x8 qf[2];
  {
    const u16* qp = qkv + (long)(b * 1024 + q0 + l15) * LD + h * 64 + l4 * 8;
    qf[0] = *(const bf16x8*)qp;
    qf[1] = *(const bf16x8*)(qp + 32);
  }
  f32x4 acc[4] = {};
  float m_run = -1e30f, l_run = 0.0f;
  int kv_end = qblk * 64 + 64;

  for (int kv0 = 0; kv0 < kv_end; kv0 += 32) {
    {
      int r = tid >> 3, c = (tid & 7) * 8;
      const u16* kp = qkv + (long)(b * 1024 + kv0 + r) * LD + 1024 + h * 64 + c;
      *(u16x8*)&Kt[r * 64 + c] = *(const u16x8*)kp;
      u16x8 vv = *(const u16x8*)(kp + 1024);
#pragma unroll
      for (int j = 0; j < 8; j++) VT[(c + j) * 32 + r] = vv[j];
    }
    __syncthreads();
    if (kv0 < q0 + 16) {
      float p[8];
      float pmax = -1e30f;
      int qg = q0 + l15;
#pragma unroll
      for (int ks = 0; ks < 2; ks++) {
        f32x4 st = {};
#pragma unroll
        for (int kc = 0; kc < 2; kc++) {
          bf16x8 kf = *(const bf16x8*)&Kt[(ks * 16 + l15) * 64 + kc * 32 + l4 * 8];
          st = __builtin_amdgcn_mfma_f32_16x16x32_bf16(kf, qf[kc], st, 0, 0, 0);
        }
#pragma unroll
        for (int r = 0; r < 4; r++) {
          int kvg = kv0 + ks * 16 + l4 * 4 + r;
          float v = st[r] * 0.125f;
          if (kvg > qg) v = -1e30f;
          p[ks * 4 + r] = v;
          pmax = fmaxf(pmax, v);
        }
      }
      pmax = fmaxf(pmax, __shfl_xor(pmax, 16, 64));
      pmax = fmaxf(pmax, __shfl_xor(pmax, 32, 64));
      float m_new = fmaxf(m_run, pmax);
      float alpha = __expf(m_run - m_new);
      float rsum = 0.f;
#pragma unroll
      for (int i = 0; i < 8; i++) {
        p[i] = __expf(p[i] - m_new);
        rsum += p[i];
      }
      rsum += __shfl_xor(rsum, 16, 64);
      rsum += __shfl_xor(rsum, 32, 64);
      l_run = l_run * alpha + rsum;
      m_run = m_new;
      float af4[4];
#pragma unroll
      for (int r = 0; r < 4; r++) af4[r] = __shfl(alpha, l4 * 4 + r, 64);
#pragma unroll
      for (int i = 0; i < 4; i++) {
#pragma unroll
        for (int r = 0; r < 4; r++) acc[i][r] *= af4[r];
      }
      u16* pw = &Pl[wave][0];
#pragma unroll
      for (int i = 0; i < 8; i++) {
        int ks = i >> 2, r = i & 3;
        pw[l15 * 32 + ks * 16 + l4 * 4 + r] = f2bf(p[i]);
      }
      bf16x8 pa = *(const bf16x8*)&pw[l15 * 32 + l4 * 8];
#pragma unroll
      for (int i = 0; i < 4; i++) {
        bf16x8 vf = *(const bf16x8*)&VT[(i * 16 + l15) * 32 + l4 * 8];
        acc[i] = __builtin_amdgcn_mfma_f32_16x16x32_bf16(pa, vf, acc[i], 0, 0, 0);
      }
    }
    __syncthreads();
  }

  float linv[4];
#pragma unroll
  for (int r = 0; r < 4; r++) {
    float lv = __shfl(l_run, l4 * 4 + r, 64);
    linv[r] = 1.0f / lv;
  }
#pragma unroll
  for (int r = 0; r < 4; r++) {
    int q = l4 * 4 + r;
    long nrow = (long)b * 1024 + q0 + q;
    float4 s4 = reinterpret_cast<const float4*>(score_a)[nrow];
    float se[4] = {s4.x, s4.y, s4.z, s4.w};
#pragma unroll
    for (int i = 0; i < 4; i++) {
      float v = acc[i][r] * linv[r];
      int d = h * 64 + i * 16 + l15;
#pragma unroll
      for (int e = 0; e < 4; e++) A_pr[nrow * 4096 + e * 1024 + d] = f2bf(se[e] * v);
    }
  }
}

// ---------------- out = y + sum_e score2[e]*bp2[e] --------------------------------
__global__ __launch_bounds__(256) void init_out(const float* __restrict__ y,
                                                const float* __restrict__ score_m,
                                                const float* __restrict__ bp2,
                                                float* __restrict__ out) {
  int n = blockIdx.x, t = threadIdx.x;
  float4 s4 = reinterpret_cast<const float4*>(score_m)[n];
#pragma unroll
  for (int i = 0; i < 4; i++) {
    int d = i * 256 + t;
    long idx = (long)n * D_ + d;
    out[idx] = y[idx] + s4.x * bp2[d] + s4.y * bp2[D_ + d] + s4.z * bp2[2 * D_ + d] +
               s4.w * bp2[3 * D_ + d];
  }
}

extern "C" void kernel_launch(void* const* d_in, const int* in_sizes, int n_in, void* d_out,
                              int out_size, void* d_ws, size_t ws_size, hipStream_t stream) {
  (void)in_sizes; (void)n_in; (void)out_size; (void)ws_size;
  const float* x    = (const float*)d_in[0];
  const float* Wr_a = (const float*)d_in[1];
  const float* br_a = (const float*)d_in[2];
  const float* g_a  = (const float*)d_in[3];
  const float* b_a  = (const float*)d_in[4];
  const float* Wqkv = (const float*)d_in[5];
  const float* bqkv = (const float*)d_in[6];
  const float* Wpr  = (const float*)d_in[7];
  const float* bpr  = (const float*)d_in[8];
  const float* Wr_m = (const float*)d_in[9];
  const float* br_m = (const float*)d_in[10];
  const float* g_m  = (const float*)d_in[11];
  const float* b_m  = (const float*)d_in[12];
  const float* Wfc  = (const float*)d_in[13];
  const float* bfc  = (const float*)d_in[14];
  const float* Wp2  = (const float*)d_in[15];
  const float* bp2  = (const float*)d_in[16];
  float* out = (float*)d_out;

  // ---- compact workspace: 128.13 MB total with region reuse (stream-ordered) ----
  char* ws = (char*)d_ws;
  const size_t oW = 0;                        // 24MB: wt_qkv -> wt_pr -> per-e {wt_fc_e, wt_p2_e}
  const size_t oA = 25165824;                 // 32MB: A_a -> A_fc
  const size_t oQ = oA + 33554432;            // 24MB: qkvb
  const size_t oP = oQ + 25165824;            // 32MB: A_pr -> inter
  const size_t oY = oP + 33554432;            // 16MB: ybuf
  const size_t oS = oY + 16777216;            // scores
  u16* wt_qkv = (u16*)(ws + oW);
  u16* wt_pr  = (u16*)(ws + oW);
  u16* wt_fce = (u16*)(ws + oW);
  u16* wt_p2e = (u16*)(ws + oW + (size_t)4096 * 1024 * 2);
  u16* A_a    = (u16*)(ws + oA);
  u16* A_fc   = (u16*)(ws + oA);
  u16* qkvb   = (u16*)(ws + oQ);
  u16* A_pr   = (u16*)(ws + oP);
  u16* inter  = (u16*)(ws + oP);
  float* ybuf = (float*)(ws + oY);
  float* score_a = (float*)(ws + oS);
  float* score_m = (float*)(ws + oS + 65536);

  dim3 tb(32, 8);
  // attention half
  tcvt<<<dim3(3072 / 32, 4096 / 32, 1), tb, 0, stream>>>(Wqkv, wt_qkv, 4096, 3072);
  ln_router_expand<<<N_, 256, 0, stream>>>(x, Wr_a, br_a, g_a, b_a, score_a, A_a,
                                           (long)1024, (long)4096, 1);
  gemm_bt<0><<<dim3(3072 / 128, 4096 / 128), 256, 0, stream>>>(
      A_a, wt_qkv, 4096, 3072, score_a, bqkv, nullptr, 0, qkvb, nullptr);
  attn_kernel<<<dim3(S_ / 64, B_ * H_), 256, 0, stream>>>(qkvb, score_a, A_pr);
  tcvt<<<dim3(1024 / 32, 4096 / 32, 1), tb, 0, stream>>>(Wpr, wt_pr, 4096, 1024);
  gemm_bt<1><<<dim3(1024 / 128, 4096 / 128), 256, 0, stream>>>(
      A_pr, wt_pr, 4096, 1024, score_a, bpr, x, 0, nullptr, ybuf);

  // MLP half
  ln_router_expand<<<N_, 256, 0, stream>>>(ybuf, Wr_m, br_m, g_m, b_m, score_m, A_fc,
                                           (long)N_ * 1024, (long)1024, 0);
  init_out<<<N_, 256, 0, stream>>>(ybuf, score_m, bp2, out);
  for (int e = 0; e < 4; e++) {
    tcvt<<<dim3(4096 / 32, 1024 / 32, 1), tb, 0, stream>>>(
        Wfc + (size_t)e * 1024 * 4096, wt_fce, 1024, 4096);
    tcvt<<<dim3(1024 / 32, 4096 / 32, 1), tb, 0, stream>>>(
        Wp2 + (size_t)e * 4096 * 1024, wt_p2e, 4096, 1024);
    gemm_bt<2><<<dim3(4096 / 128, 4096 / 128), 256, 0, stream>>>(
        A_fc + (size_t)e * N_ * 1024, wt_fce, 1024, 4096, score_m,
        bfc + e * 4096, nullptr, e, inter, nullptr);
    gemm_bt<3><<<dim3(1024 / 128, 4096 / 128), 256, 0, stream>>>(
        inter, wt_p2e, 4096, 1024, nullptr, nullptr, nullptr, 0,
        nullptr, out);
  }
}

// Round 3
// 851.815 us; speedup vs baseline: 1.2700x; 1.2700x over previous
//
#include <hip/hip_runtime.h>
#include <hip/hip_bf16.h>

typedef __bf16 bf16x8 __attribute__((ext_vector_type(8)));
typedef float f32x4 __attribute__((ext_vector_type(4)));
typedef unsigned short u16;
typedef u16 u16x8 __attribute__((ext_vector_type(8)));

#define B_ 4
#define S_ 1024
#define D_ 1024
#define E_ 4
#define H_ 16
#define FF_ 4096
#define N_ 4096

__device__ __forceinline__ u16 f2bf(float f) {
  __hip_bfloat16 h = __float2bfloat16(f);
  return *reinterpret_cast<u16*>(&h);
}
__device__ __forceinline__ float bf2f(u16 v) {
  return __uint_as_float(((unsigned)v) << 16);
}

#define BAR()                         \
  {                                   \
    asm volatile("" ::: "memory");    \
    __builtin_amdgcn_s_barrier();     \
    asm volatile("" ::: "memory");    \
  }

// ---------------- transpose + f32->bf16 convert: dst[c][r] = src[r][c] ----------------
__global__ __launch_bounds__(256) void tcvt(const float* __restrict__ src,
                                            u16* __restrict__ dst, int R, int C) {
  __shared__ float t[32][33];
  int r0 = blockIdx.y * 32, c0 = blockIdx.x * 32;
  int tx = threadIdx.x, ty = threadIdx.y;  // 32 x 8
#pragma unroll
  for (int i = 0; i < 4; i++)
    t[ty + i * 8][tx] = src[(long)(r0 + ty + i * 8) * C + c0 + tx];
  __syncthreads();
#pragma unroll
  for (int i = 0; i < 4; i++)
    dst[(long)(c0 + ty + i * 8) * R + r0 + tx] = f2bf(t[tx][ty + i * 8]);
}

// ---------------- LN + router softmax + per-expert expand ----------------
__global__ __launch_bounds__(256) void ln_router_expand(
    const float* __restrict__ X, const float* __restrict__ Wr, const float* __restrict__ br,
    const float* __restrict__ g, const float* __restrict__ bb,
    float* __restrict__ score_out, u16* __restrict__ Aout,
    long stride_e, long stride_n, int scale_flag) {
  int n = blockIdx.x, t = threadIdx.x;
  int lane = t & 63, wave = t >> 6;
  const float* xr = X + (long)n * D_;
  float xv[4];
  float vals[6] = {0.f, 0.f, 0.f, 0.f, 0.f, 0.f};
#pragma unroll
  for (int i = 0; i < 4; i++) {
    int d = i * 256 + t;
    float v = xr[d];
    xv[i] = v;
    vals[0] += v;
    vals[1] += v * v;
    float4 w = reinterpret_cast<const float4*>(Wr)[d];
    vals[2] += v * w.x; vals[3] += v * w.y; vals[4] += v * w.z; vals[5] += v * w.w;
  }
#pragma unroll
  for (int o = 1; o < 64; o <<= 1) {
#pragma unroll
    for (int j = 0; j < 6; j++) vals[j] += __shfl_xor(vals[j], o, 64);
  }
  __shared__ float red[4][6];
  if (lane == 0) {
#pragma unroll
    for (int j = 0; j < 6; j++) red[wave][j] = vals[j];
  }
  __syncthreads();
  float tot[6];
#pragma unroll
  for (int j = 0; j < 6; j++) tot[j] = red[0][j] + red[1][j] + red[2][j] + red[3][j];
  float mean = tot[0] * (1.0f / D_);
  float var = tot[1] * (1.0f / D_) - mean * mean;
  float rstd = rsqrtf(var + 1e-5f);
  float lg0 = tot[2] + br[0], lg1 = tot[3] + br[1], lg2 = tot[4] + br[2], lg3 = tot[5] + br[3];
  float mx = fmaxf(fmaxf(lg0, lg1), fmaxf(lg2, lg3));
  float e0 = __expf(lg0 - mx), e1 = __expf(lg1 - mx), e2 = __expf(lg2 - mx), e3 = __expf(lg3 - mx);
  float inv = 1.0f / (e0 + e1 + e2 + e3);
  float sc[4] = {e0 * inv, e1 * inv, e2 * inv, e3 * inv};
  if (t == 0) {
    float4 s4 = make_float4(sc[0], sc[1], sc[2], sc[3]);
    *reinterpret_cast<float4*>(&score_out[(long)n * 4]) = s4;
  }
#pragma unroll
  for (int i = 0; i < 4; i++) {
    int d = i * 256 + t;
    float hn = (xv[i] - mean) * rstd;
#pragma unroll
    for (int e = 0; e < 4; e++) {
      float val = hn * g[e * D_ + d] + bb[e * D_ + d];
      if (scale_flag) val *= sc[e];
      Aout[(long)e * stride_e + (long)n * stride_n + d] = f2bf(val);
    }
  }
}

// ================= 8-phase 256x256 GEMM: C = A[M,K] * Bt[N,K]^T ====================
// LDS: 2 buffers x { A-kc0, A-kc1, B-kc0, B-kc1 } regions of [256 rows][32 u16].
// Swizzle: phys 16B-chunk-in-row = logical ^ ((row>>1)&3)  (both on gload src & ds_read)
// Schedule per K-tile t (buf p): 4 phases; stage A-kc1^{t+1},B-kc1^{t+1} (p1,p2 -> buf p^1),
// A-kc0^{t+2},B-kc0^{t+2} (p3,p4 -> dead regions of buf p). One s_waitcnt vmcnt(4) at p4.
// MODE 0: outb = bf16(acc + sum_e score[row][e]*bias[e*N+col])       (qkv)
// MODE 2: outb = bf16(score[row*4+eidx] * gelu(acc + bias[col]))     (fc)
// MODE 4: outb[z*zstride + ...] = bf16(acc)                          (splitK partials)
template <int MODE>
__global__ __launch_bounds__(512, 2) void g8(
    const u16* __restrict__ A, const u16* __restrict__ Bt, int K, int N, int kslice,
    const float* __restrict__ score, const float* __restrict__ bias,
    u16* __restrict__ outb, int eidx, long zstride) {
  __shared__ __align__(16) u16 lds0[65536];  // 128 KiB
  const int tid = threadIdx.x;
  const int w = tid >> 6, lane = tid & 63;
  const int l15 = lane & 15, l4 = lane >> 4;
  const int wr = w >> 2, wc = w & 3;
  const long bm = (long)blockIdx.y * 256, bn = (long)blockIdx.x * 256;
  const int z = blockIdx.z;
  const long k0 = (long)z * kslice;
  const int nt = kslice >> 6;

  // staging geometry: wave w, load j covers rows w*32+j*16 .. +15 of the region
  const int cp = lane & 3;
  const int sr0 = w * 32 + (lane >> 2);
  const int sr1 = sr0 + 16;
  const int cl0 = cp ^ ((sr0 >> 1) & 3);
  const int cl1 = cp ^ ((sr1 >> 1) & 3);
  const u16* gA0 = A + (bm + sr0) * (long)K + k0 + cl0 * 8;
  const u16* gA1 = A + (bm + sr1) * (long)K + k0 + cl1 * 8;
  const u16* gB0 = Bt + (bn + sr0) * (long)K + k0 + cl0 * 8;
  const u16* gB1 = Bt + (bn + sr1) * (long)K + k0 + cl1 * 8;
  const int e0 = w * 1024;        // (w*2+0)*512 u16
  const int e1 = w * 1024 + 512;  // (w*2+1)*512 u16

  // frag-read bases (u16 units within a region)
  const int chA = l4 ^ ((l15 >> 1) & 3);
  const int rdA = (wr * 128 + l15) * 32 + chA * 8;  // + mi*512
  const int rdB = (wc * 64 + l15) * 32 + chA * 8;   // + ni*512

#define GLD(gsrc, ldsoff)                                                              \
  __builtin_amdgcn_global_load_lds(                                                    \
      (const __attribute__((address_space(1))) void*)(gsrc),                           \
      (__attribute__((address_space(3))) void*)(lds0 + (ldsoff)), 16, 0, 0)

  // -------- prologue: tile0 (4 regions) + tile1 kc0 --------
  GLD(gA0, 0 + e0);
  GLD(gA1, 0 + e1);
  GLD(gB0, 16384 + e0);
  GLD(gB1, 16384 + e1);
  GLD(gA0 + 32, 8192 + e0);
  GLD(gA1 + 32, 8192 + e1);
  GLD(gB0 + 32, 24576 + e0);
  GLD(gB1 + 32, 24576 + e1);
  if (nt > 1) {
    GLD(gA0 + 64, 32768 + e0);
    GLD(gA1 + 64, 32768 + e1);
    GLD(gB0 + 64, 32768 + 16384 + e0);
    GLD(gB1 + 64, 32768 + 16384 + e1);
    asm volatile("s_waitcnt vmcnt(4)" ::: "memory");
  } else {
    asm volatile("s_waitcnt vmcnt(0)" ::: "memory");
  }
  BAR();

  f32x4 acc[8][4] = {};
  bf16x8 a[4], b[4];

  for (int t = 0; t < nt; ++t) {
    const int base = (t & 1) * 32768;
    const int nb = base ^ 32768;
    // ---------- phase 1 (kc0, mh0): read A mi0-3 + B ni0-3; stage A-kc1^{t+1} ----------
#pragma unroll
    for (int i = 0; i < 4; i++) a[i] = *(const bf16x8*)(lds0 + base + rdA + i * 512);
#pragma unroll
    for (int i = 0; i < 4; i++) b[i] = *(const bf16x8*)(lds0 + base + 16384 + rdB + i * 512);
    if (t + 1 < nt) {
      long ko = (long)(t + 1) * 64 + 32;
      GLD(gA0 + ko, nb + 8192 + e0);
      GLD(gA1 + ko, nb + 8192 + e1);
    }
    BAR();
    __builtin_amdgcn_s_setprio(1);
#pragma unroll
    for (int mi = 0; mi < 4; mi++)
#pragma unroll
      for (int ni = 0; ni < 4; ni++)
        acc[mi][ni] = __builtin_amdgcn_mfma_f32_16x16x32_bf16(a[mi], b[ni], acc[mi][ni], 0, 0, 0);
    __builtin_amdgcn_s_setprio(0);
    BAR();
    // ---------- phase 2 (kc0, mh1): read A mi4-7; stage B-kc1^{t+1} ----------
#pragma unroll
    for (int i = 0; i < 4; i++) a[i] = *(const bf16x8*)(lds0 + base + rdA + (4 + i) * 512);
    if (t + 1 < nt) {
      long ko = (long)(t + 1) * 64 + 32;
      GLD(gB0 + ko, nb + 24576 + e0);
      GLD(gB1 + ko, nb + 24576 + e1);
    }
    BAR();
    __builtin_amdgcn_s_setprio(1);
#pragma unroll
    for (int mi = 0; mi < 4; mi++)
#pragma unroll
      for (int ni = 0; ni < 4; ni++)
        acc[4 + mi][ni] =
            __builtin_amdgcn_mfma_f32_16x16x32_bf16(a[mi], b[ni], acc[4 + mi][ni], 0, 0, 0);
    __builtin_amdgcn_s_setprio(0);
    BAR();
    // ---------- phase 3 (kc1, mh0): read A mi0-3 + B; stage A-kc0^{t+2} ----------
#pragma unroll
    for (int i = 0; i < 4; i++) a[i] = *(const bf16x8*)(lds0 + base + 8192 + rdA + i * 512);
#pragma unroll
    for (int i = 0; i < 4; i++) b[i] = *(const bf16x8*)(lds0 + base + 24576 + rdB + i * 512);
    if (t + 2 < nt) {
      long ko = (long)(t + 2) * 64;
      GLD(gA0 + ko, base + e0);
      GLD(gA1 + ko, base + e1);
    }
    BAR();
    __builtin_amdgcn_s_setprio(1);
#pragma unroll
    for (int mi = 0; mi < 4; mi++)
#pragma unroll
      for (int ni = 0; ni < 4; ni++)
        acc[mi][ni] = __builtin_amdgcn_mfma_f32_16x16x32_bf16(a[mi], b[ni], acc[mi][ni], 0, 0, 0);
    __builtin_amdgcn_s_setprio(0);
    BAR();
    // ---------- phase 4 (kc1, mh1): read A mi4-7; stage B-kc0^{t+2}; vmcnt ----------
#pragma unroll
    for (int i = 0; i < 4; i++)
      a[i] = *(const bf16x8*)(lds0 + base + 8192 + rdA + (4 + i) * 512);
    if (t + 2 < nt) {
      long ko = (long)(t + 2) * 64;
      GLD(gB0 + ko, base + 16384 + e0);
      GLD(gB1 + ko, base + 16384 + e1);
      asm volatile("s_waitcnt vmcnt(4)" ::: "memory");
    } else {
      asm volatile("s_waitcnt vmcnt(0)" ::: "memory");
    }
    BAR();
    __builtin_amdgcn_s_setprio(1);
#pragma unroll
    for (int mi = 0; mi < 4; mi++)
#pragma unroll
      for (int ni = 0; ni < 4; ni++)
        acc[4 + mi][ni] =
            __builtin_amdgcn_mfma_f32_16x16x32_bf16(a[mi], b[ni], acc[4 + mi][ni], 0, 0, 0);
    __builtin_amdgcn_s_setprio(0);
    BAR();
  }
#undef GLD

  // -------- epilogue --------
  const long zoff = (long)z * zstride;
#pragma unroll
  for (int ni = 0; ni < 4; ni++) {
    long col = bn + wc * 64 + ni * 16 + l15;
    float b4[4];
    float bcol = 0.0f;
    if (MODE == 0) {
#pragma unroll
      for (int e = 0; e < 4; e++) b4[e] = bias[(long)e * N + col];
    } else if (MODE == 2) {
      bcol = bias[col];
    }
#pragma unroll
    for (int mi = 0; mi < 8; mi++) {
#pragma unroll
      for (int r = 0; r < 4; r++) {
        long row = bm + wr * 128 + mi * 16 + l4 * 4 + r;
        float v = acc[mi][ni][r];
        if (MODE == 0) {
          float4 s4 = reinterpret_cast<const float4*>(score)[row];
          v += s4.x * b4[0] + s4.y * b4[1] + s4.z * b4[2] + s4.w * b4[3];
          outb[row * (long)N + col] = f2bf(v);
        } else if (MODE == 2) {
          float u = v + bcol;
          float zz = 0.7978845608f * (u + 0.044715f * u * u * u);
          float tt = __expf(2.0f * zz);
          float gel = u * (1.0f - 1.0f / (tt + 1.0f));
          outb[row * (long)N + col] = f2bf(gel * score[row * 4 + eidx]);
        } else {
          outb[zoff + row * (long)N + col] = f2bf(v);
        }
      }
    }
  }
}

// ---------------- flash attention (causal), writes A_pr = score_e * attn_out --------
__global__ __launch_bounds__(256) void attn_kernel(const u16* __restrict__ qkv,
                                                   const float* __restrict__ score_a,
                                                   u16* __restrict__ A_pr) {
  __shared__ __align__(16) u16 Kt[32 * 64];
  __shared__ __align__(16) u16 VT[64 * 32];
  __shared__ __align__(16) u16 Pl[4][16 * 32];
  int tid = threadIdx.x, wave = tid >> 6, lane = tid & 63;
  int l15 = lane & 15, l4 = lane >> 4;
  int qblk = blockIdx.x, bh = blockIdx.y;
  int b = bh >> 4, h = bh & 15;
  int q0 = qblk * 64 + wave * 16;
  const long LD = 3072;

  bf16x8 qf[2];
  {
    const u16* qp = qkv + (long)(b * 1024 + q0 + l15) * LD + h * 64 + l4 * 8;
    qf[0] = *(const bf16x8*)qp;
    qf[1] = *(const bf16x8*)(qp + 32);
  }
  f32x4 acc[4] = {};
  float m_run = -1e30f, l_run = 0.0f;
  int kv_end = qblk * 64 + 64;

  for (int kv0 = 0; kv0 < kv_end; kv0 += 32) {
    {
      int r = tid >> 3, c = (tid & 7) * 8;
      const u16* kp = qkv + (long)(b * 1024 + kv0 + r) * LD + 1024 + h * 64 + c;
      *(u16x8*)&Kt[r * 64 + c] = *(const u16x8*)kp;
      u16x8 vv = *(const u16x8*)(kp + 1024);
#pragma unroll
      for (int j = 0; j < 8; j++) VT[(c + j) * 32 + r] = vv[j];
    }
    __syncthreads();
    if (kv0 < q0 + 16) {
      float p[8];
      float pmax = -1e30f;
      int qg = q0 + l15;
#pragma unroll
      for (int ks = 0; ks < 2; ks++) {
        f32x4 st = {};
#pragma unroll
        for (int kc = 0; kc < 2; kc++) {
          bf16x8 kf = *(const bf16x8*)&Kt[(ks * 16 + l15) * 64 + kc * 32 + l4 * 8];
          st = __builtin_amdgcn_mfma_f32_16x16x32_bf16(kf, qf[kc], st, 0, 0, 0);
        }
#pragma unroll
        for (int r = 0; r < 4; r++) {
          int kvg = kv0 + ks * 16 + l4 * 4 + r;
          float v = st[r] * 0.125f;
          if (kvg > qg) v = -1e30f;
          p[ks * 4 + r] = v;
          pmax = fmaxf(pmax, v);
        }
      }
      pmax = fmaxf(pmax, __shfl_xor(pmax, 16, 64));
      pmax = fmaxf(pmax, __shfl_xor(pmax, 32, 64));
      float m_new = fmaxf(m_run, pmax);
      float alpha = __expf(m_run - m_new);
      float rsum = 0.f;
#pragma unroll
      for (int i = 0; i < 8; i++) {
        p[i] = __expf(p[i] - m_new);
        rsum += p[i];
      }
      rsum += __shfl_xor(rsum, 16, 64);
      rsum += __shfl_xor(rsum, 32, 64);
      l_run = l_run * alpha + rsum;
      m_run = m_new;
      float af4[4];
#pragma unroll
      for (int r = 0; r < 4; r++) af4[r] = __shfl(alpha, l4 * 4 + r, 64);
#pragma unroll
      for (int i = 0; i < 4; i++) {
#pragma unroll
        for (int r = 0; r < 4; r++) acc[i][r] *= af4[r];
      }
      u16* pw = &Pl[wave][0];
#pragma unroll
      for (int i = 0; i < 8; i++) {
        int ks = i >> 2, r = i & 3;
        pw[l15 * 32 + ks * 16 + l4 * 4 + r] = f2bf(p[i]);
      }
      bf16x8 pa = *(const bf16x8*)&pw[l15 * 32 + l4 * 8];
#pragma unroll
      for (int i = 0; i < 4; i++) {
        bf16x8 vf = *(const bf16x8*)&VT[(i * 16 + l15) * 32 + l4 * 8];
        acc[i] = __builtin_amdgcn_mfma_f32_16x16x32_bf16(pa, vf, acc[i], 0, 0, 0);
      }
    }
    __syncthreads();
  }

  float linv[4];
#pragma unroll
  for (int r = 0; r < 4; r++) {
    float lv = __shfl(l_run, l4 * 4 + r, 64);
    linv[r] = 1.0f / lv;
  }
#pragma unroll
  for (int r = 0; r < 4; r++) {
    int q = l4 * 4 + r;
    long nrow = (long)b * 1024 + q0 + q;
    float4 s4 = reinterpret_cast<const float4*>(score_a)[nrow];
    float se[4] = {s4.x, s4.y, s4.z, s4.w};
#pragma unroll
    for (int i = 0; i < 4; i++) {
      float v = acc[i][r] * linv[r];
      int d = h * 64 + i * 16 + l15;
#pragma unroll
      for (int e = 0; e < 4; e++) A_pr[nrow * 4096 + e * 1024 + d] = f2bf(se[e] * v);
    }
  }
}

// ---------------- ybuf = x + sum_e s_a*bpr_e + sum_z prt_z ----------------
__global__ __launch_bounds__(256) void reduce_y(const float* __restrict__ x,
                                                const float* __restrict__ score_a,
                                                const float* __restrict__ bpr,
                                                const u16* __restrict__ prt,
                                                float* __restrict__ ybuf) {
  int n = blockIdx.x, t = threadIdx.x;
  float4 s4 = reinterpret_cast<const float4*>(score_a)[n];
#pragma unroll
  for (int i = 0; i < 4; i++) {
    int d = i * 256 + t;
    long idx = (long)n * D_ + d;
    float v = x[idx] + s4.x * bpr[d] + s4.y * bpr[D_ + d] + s4.z * bpr[2 * D_ + d] +
              s4.w * bpr[3 * D_ + d];
#pragma unroll
    for (int zz = 0; zz < 4; zz++) v += bf2f(prt[(long)zz * 4194304 + idx]);
    ybuf[idx] = v;
  }
}

// ---------------- out accumulate: FIRST: out = ybuf + bias-mix + sum_z; else out += sum_z
template <int FIRST>
__global__ __launch_bounds__(256) void accum_out(const float* __restrict__ ybuf,
                                                 const float* __restrict__ score_m,
                                                 const float* __restrict__ bp2,
                                                 const u16* __restrict__ p2t,
                                                 float* __restrict__ out) {
  int n = blockIdx.x, t = threadIdx.x;
#pragma unroll
  for (int i = 0; i < 4; i++) {
    int d = i * 256 + t;
    long idx = (long)n * D_ + d;
    float v;
    if (FIRST) {
      float4 s4 = reinterpret_cast<const float4*>(score_m)[n];
      v = ybuf[idx] + s4.x * bp2[d] + s4.y * bp2[D_ + d] + s4.z * bp2[2 * D_ + d] +
          s4.w * bp2[3 * D_ + d];
    } else {
      v = out[idx];
    }
#pragma unroll
    for (int zz = 0; zz < 4; zz++) v += bf2f(p2t[(long)zz * 4194304 + idx]);
    out[idx] = v;
  }
}

extern "C" void kernel_launch(void* const* d_in, const int* in_sizes, int n_in, void* d_out,
                              int out_size, void* d_ws, size_t ws_size, hipStream_t stream) {
  (void)in_sizes; (void)n_in; (void)out_size; (void)ws_size;
  const float* x    = (const float*)d_in[0];
  const float* Wr_a = (const float*)d_in[1];
  const float* br_a = (const float*)d_in[2];
  const float* g_a  = (const float*)d_in[3];
  const float* b_a  = (const float*)d_in[4];
  const float* Wqkv = (const float*)d_in[5];
  const float* bqkv = (const float*)d_in[6];
  const float* Wpr  = (const float*)d_in[7];
  const float* bpr  = (const float*)d_in[8];
  const float* Wr_m = (const float*)d_in[9];
  const float* br_m = (const float*)d_in[10];
  const float* g_m  = (const float*)d_in[11];
  const float* b_m  = (const float*)d_in[12];
  const float* Wfc  = (const float*)d_in[13];
  const float* bfc  = (const float*)d_in[14];
  const float* Wp2  = (const float*)d_in[15];
  const float* bp2  = (const float*)d_in[16];
  float* out = (float*)d_out;

  // ---- workspace: 136.25 MB, stream-ordered region reuse ----
  char* ws = (char*)d_ws;
  const size_t oW = 0;                  // 24MB: wt_qkv -> wt_pr -> {wt_fce, wt_p2e}
  const size_t oA = 25165824;           // 32MB: A_a -> prt(bf16) -> A_fc
  const size_t oQ = oA + 33554432;      // 32MB: qkvb -> p2t(bf16)
  const size_t oP = oQ + 33554432;      // 32MB: A_pr -> inter
  const size_t oY = oP + 33554432;      // 16MB: ybuf
  const size_t oS = oY + 16777216;      // scores
  u16* wt_qkv  = (u16*)(ws + oW);
  u16* wt_pr   = (u16*)(ws + oW);
  u16* wt_fce  = (u16*)(ws + oW);
  u16* wt_p2e  = (u16*)(ws + oW + (size_t)8 * 1024 * 1024);
  u16* A_a     = (u16*)(ws + oA);
  u16* prt     = (u16*)(ws + oA);
  u16* A_fc    = (u16*)(ws + oA);
  u16* qkvb    = (u16*)(ws + oQ);
  u16* p2t     = (u16*)(ws + oQ);
  u16* A_pr    = (u16*)(ws + oP);
  u16* inter   = (u16*)(ws + oP);
  float* ybuf  = (float*)(ws + oY);
  float* score_a = (float*)(ws + oS);
  float* score_m = (float*)(ws + oS + 65536);

  dim3 tb(32, 8);
  // ---- attention half ----
  tcvt<<<dim3(3072 / 32, 4096 / 32), tb, 0, stream>>>(Wqkv, wt_qkv, 4096, 3072);
  ln_router_expand<<<N_, 256, 0, stream>>>(x, Wr_a, br_a, g_a, b_a, score_a, A_a,
                                           (long)1024, (long)4096, 1);
  g8<0><<<dim3(3072 / 256, 4096 / 256, 1), 512, 0, stream>>>(
      A_a, wt_qkv, 4096, 3072, 4096, score_a, bqkv, qkvb, 0, 0L);
  attn_kernel<<<dim3(S_ / 64, B_ * H_), 256, 0, stream>>>(qkvb, score_a, A_pr);
  tcvt<<<dim3(1024 / 32, 4096 / 32), tb, 0, stream>>>(Wpr, wt_pr, 4096, 1024);
  g8<4><<<dim3(1024 / 256, 4096 / 256, 4), 512, 0, stream>>>(
      A_pr, wt_pr, 4096, 1024, 1024, nullptr, nullptr, prt, 0, (long)4096 * 1024);
  reduce_y<<<N_, 256, 0, stream>>>(x, score_a, bpr, prt, ybuf);

  // ---- MLP half ----
  ln_router_expand<<<N_, 256, 0, stream>>>(ybuf, Wr_m, br_m, g_m, b_m, score_m, A_fc,
                                           (long)N_ * 1024, (long)1024, 0);
  for (int e = 0; e < 4; e++) {
    tcvt<<<dim3(4096 / 32, 1024 / 32), tb, 0, stream>>>(
        Wfc + (size_t)e * 1024 * 4096, wt_fce, 1024, 4096);
    g8<2><<<dim3(4096 / 256, 4096 / 256, 1), 512, 0, stream>>>(
        A_fc + (size_t)e * N_ * 1024, wt_fce, 1024, 4096, 1024, score_m,
        bfc + e * 4096, inter, e, 0L);
    tcvt<<<dim3(1024 / 32, 4096 / 32), tb, 0, stream>>>(
        Wp2 + (size_t)e * 4096 * 1024, wt_p2e, 4096, 1024);
    g8<4><<<dim3(1024 / 256, 4096 / 256, 4), 512, 0, stream>>>(
        inter, wt_p2e, 4096, 1024, 1024, nullptr, nullptr, p2t, 0, (long)4096 * 1024);
    if (e == 0) {
      accum_out<1><<<N_, 256, 0, stream>>>(ybuf, score_m, bp2, p2t, out);
    } else {
      accum_out<0><<<N_, 256, 0, stream>>>(nullptr, nullptr, nullptr, p2t, out);
    }
  }
}

// Round 6
// 804.210 us; speedup vs baseline: 1.3452x; 1.0592x over previous
//
#include <hip/hip_runtime.h>
#include <hip/hip_bf16.h>

typedef __bf16 bf16x8 __attribute__((ext_vector_type(8)));
typedef float f32x4 __attribute__((ext_vector_type(4)));
typedef unsigned short u16;
typedef u16 u16x8 __attribute__((ext_vector_type(8)));

#define B_ 4
#define S_ 1024
#define D_ 1024
#define E_ 4
#define H_ 16
#define FF_ 4096
#define N_ 4096

__device__ __forceinline__ u16 f2bf(float f) {
  __hip_bfloat16 h = __float2bfloat16(f);
  return *reinterpret_cast<u16*>(&h);
}
__device__ __forceinline__ float bf2f(u16 v) {
  return __uint_as_float(((unsigned)v) << 16);
}

#define BAR()                         \
  {                                   \
    asm volatile("" ::: "memory");    \
    __builtin_amdgcn_s_barrier();     \
    asm volatile("" ::: "memory");    \
  }

// ---------------- transpose + f32->bf16 convert: dst[c][r] = src[r][c] ----------------
__global__ __launch_bounds__(256) void tcvt(const float* __restrict__ src,
                                            u16* __restrict__ dst, int R, int C) {
  __shared__ float t[32][33];
  int r0 = blockIdx.y * 32, c0 = blockIdx.x * 32;
  int tx = threadIdx.x, ty = threadIdx.y;  // 32 x 8
#pragma unroll
  for (int i = 0; i < 4; i++)
    t[ty + i * 8][tx] = src[(long)(r0 + ty + i * 8) * C + c0 + tx];
  __syncthreads();
#pragma unroll
  for (int i = 0; i < 4; i++)
    dst[(long)(c0 + ty + i * 8) * R + r0 + tx] = f2bf(t[tx][ty + i * 8]);
}

// ---------------- LN + router softmax + per-expert expand ----------------
// YMODE=0: input row = X[n]. YMODE=1: row = X[n] + sum_e score_a[e]*bpr[e] + sum_z prt_z
// (fused attention-output reduction); also writes the reconstructed row to ybuf.
template <int YMODE>
__global__ __launch_bounds__(256) void ln_router_expand(
    const float* __restrict__ X, const float* __restrict__ Wr, const float* __restrict__ br,
    const float* __restrict__ g, const float* __restrict__ bb,
    float* __restrict__ score_out, u16* __restrict__ Aout,
    long stride_e, long stride_n, int scale_flag,
    const float* __restrict__ score_a, const float* __restrict__ bpr,
    const u16* __restrict__ prt, float* __restrict__ ybuf) {
  int n = blockIdx.x, t = threadIdx.x;
  int lane = t & 63, wave = t >> 6;
  const float* xr = X + (long)n * D_;
  float xv[4];
  float vals[6] = {0.f, 0.f, 0.f, 0.f, 0.f, 0.f};
  float4 sa4;
  if (YMODE) sa4 = reinterpret_cast<const float4*>(score_a)[n];
#pragma unroll
  for (int i = 0; i < 4; i++) {
    int d = i * 256 + t;
    float v = xr[d];
    if (YMODE) {
      long idx = (long)n * D_ + d;
      v += sa4.x * bpr[d] + sa4.y * bpr[D_ + d] + sa4.z * bpr[2 * D_ + d] +
           sa4.w * bpr[3 * D_ + d];
#pragma unroll
      for (int zz = 0; zz < 4; zz++) v += bf2f(prt[(long)zz * 4194304 + idx]);
      ybuf[idx] = v;
    }
    xv[i] = v;
    vals[0] += v;
    vals[1] += v * v;
    float4 w = reinterpret_cast<const float4*>(Wr)[d];
    vals[2] += v * w.x; vals[3] += v * w.y; vals[4] += v * w.z; vals[5] += v * w.w;
  }
#pragma unroll
  for (int o = 1; o < 64; o <<= 1) {
#pragma unroll
    for (int j = 0; j < 6; j++) vals[j] += __shfl_xor(vals[j], o, 64);
  }
  __shared__ float red[4][6];
  if (lane == 0) {
#pragma unroll
    for (int j = 0; j < 6; j++) red[wave][j] = vals[j];
  }
  __syncthreads();
  float tot[6];
#pragma unroll
  for (int j = 0; j < 6; j++) tot[j] = red[0][j] + red[1][j] + red[2][j] + red[3][j];
  float mean = tot[0] * (1.0f / D_);
  float var = tot[1] * (1.0f / D_) - mean * mean;
  float rstd = rsqrtf(var + 1e-5f);
  float lg0 = tot[2] + br[0], lg1 = tot[3] + br[1], lg2 = tot[4] + br[2], lg3 = tot[5] + br[3];
  float mx = fmaxf(fmaxf(lg0, lg1), fmaxf(lg2, lg3));
  float e0 = __expf(lg0 - mx), e1 = __expf(lg1 - mx), e2 = __expf(lg2 - mx), e3 = __expf(lg3 - mx);
  float inv = 1.0f / (e0 + e1 + e2 + e3);
  float sc[4] = {e0 * inv, e1 * inv, e2 * inv, e3 * inv};
  if (t == 0) {
    float4 s4 = make_float4(sc[0], sc[1], sc[2], sc[3]);
    *reinterpret_cast<float4*>(&score_out[(long)n * 4]) = s4;
  }
#pragma unroll
  for (int i = 0; i < 4; i++) {
    int d = i * 256 + t;
    float hn = (xv[i] - mean) * rstd;
#pragma unroll
    for (int e = 0; e < 4; e++) {
      float val = hn * g[e * D_ + d] + bb[e * D_ + d];
      if (scale_flag) val *= sc[e];
      Aout[(long)e * stride_e + (long)n * stride_n + d] = f2bf(val);
    }
  }
}

// ================= 8-wave 256x256 GEMM, 4-phase/K-tile, deep-pipelined ==============
// LDS regions (u16 idx): buf(t&1)*32768 + {A-kc0:0, A-kc1:8192, B-kc0:16384, B-kc1:24576}
// Stages per phase (2 gload_lds each): p1->A-kc1(t+1), p2->B-kc1(t+1),
// p3->A-kc0(t+2), p4->B-kc0(t+2). Waits: vmcnt(8) after MFMA of p2 and p4
// (per-wave queue 12 -> 8; ledger-derived tail variants 4/0).
// XCD-chunked bijective block swizzle over the flat grid (totals % 8 == 0).
// MODE 0: outb = bf16(acc + sum_e score[row][e]*bias[e*N+col])       (qkv)
// MODE 2: outb = bf16(score[row*4+eidx] * gelu(acc + bias[col]))     (fc)
// MODE 4: outb[z*zstride + ...] = bf16(acc)                          (splitK partials)
template <int MODE>
__global__ __launch_bounds__(512, 2) void g8(
    const u16* __restrict__ A, const u16* __restrict__ Bt, int K, int N, int kslice,
    const float* __restrict__ score, const float* __restrict__ bias,
    u16* __restrict__ outb, int eidx, long zstride) {
  __shared__ __align__(16) u16 lds0[65536];  // 128 KiB
  const int tid = threadIdx.x;
  const int w = tid >> 6, lane = tid & 63;
  const int l15 = lane & 15, l4 = lane >> 4;
  const int wr = w >> 2, wc = w & 3;

  // ---- XCD-aware swizzle: xcd x gets contiguous logical chunk ----
  const int gx = gridDim.x, gy = gridDim.y;
  const int total = gx * gy * gridDim.z;
  const int flat = blockIdx.x + gx * (blockIdx.y + gy * blockIdx.z);
  const int cpx = total >> 3;
  const int nf = (flat & 7) * cpx + (flat >> 3);
  const int bxi = nf % gx;
  const int tmp = nf / gx;
  const int byi = tmp % gy;
  const int z = tmp / gy;

  const long bm = (long)byi * 256, bn = (long)bxi * 256;
  const long k0 = (long)z * kslice;
  const int nt = kslice >> 6;

  // staging geometry
  const int cp = lane & 3;
  const int sr0 = w * 32 + (lane >> 2);
  const int sr1 = sr0 + 16;
  const int cl0 = cp ^ ((sr0 >> 1) & 3);
  const int cl1 = cp ^ ((sr1 >> 1) & 3);
  const u16* gA0 = A + (bm + sr0) * (long)K + k0 + cl0 * 8;
  const u16* gA1 = A + (bm + sr1) * (long)K + k0 + cl1 * 8;
  const u16* gB0 = Bt + (bn + sr0) * (long)K + k0 + cl0 * 8;
  const u16* gB1 = Bt + (bn + sr1) * (long)K + k0 + cl1 * 8;
  const int e0 = w * 1024;
  const int e1 = w * 1024 + 512;

  // frag-read bases (u16 units within a region)
  const int chA = l4 ^ ((l15 >> 1) & 3);
  const int rdA = (wr * 128 + l15) * 32 + chA * 8;  // + mi*512
  const int rdB = (wc * 64 + l15) * 32 + chA * 8;   // + ni*512

#define GLD(gsrc, ldsoff)                                                              \
  __builtin_amdgcn_global_load_lds(                                                    \
      (const __attribute__((address_space(1))) void*)(gsrc),                           \
      (__attribute__((address_space(3))) void*)(lds0 + (ldsoff)), 16, 0, 0)

  // -------- prologue: tile0 kc0, kc1; tile1 kc0 --------
  GLD(gA0, 0 + e0);
  GLD(gA1, 0 + e1);
  GLD(gB0, 16384 + e0);
  GLD(gB1, 16384 + e1);
  GLD(gA0 + 32, 8192 + e0);
  GLD(gA1 + 32, 8192 + e1);
  GLD(gB0 + 32, 24576 + e0);
  GLD(gB1 + 32, 24576 + e1);
  if (nt > 1) {
    GLD(gA0 + 64, 32768 + e0);
    GLD(gA1 + 64, 32768 + e1);
    GLD(gB0 + 64, 32768 + 16384 + e0);
    GLD(gB1 + 64, 32768 + 16384 + e1);
    asm volatile("s_waitcnt vmcnt(8)" ::: "memory");
  } else {
    asm volatile("s_waitcnt vmcnt(4)" ::: "memory");
  }
  BAR();

  f32x4 acc[8][4] = {};
  bf16x8 a[4], b[4];

  for (int t = 0; t < nt; ++t) {
    const int base = (t & 1) * 32768;
    const int nb = base ^ 32768;
    const long ko1 = (long)(t + 1) * 64 + 32;
    const long ko2 = (long)(t + 2) * 64;
    // ---------- phase 1 (kc0, mh0) ----------
#pragma unroll
    for (int i = 0; i < 4; i++) a[i] = *(const bf16x8*)(lds0 + base + rdA + i * 512);
#pragma unroll
    for (int i = 0; i < 4; i++) b[i] = *(const bf16x8*)(lds0 + base + 16384 + rdB + i * 512);
    if (t + 1 < nt) {
      GLD(gA0 + ko1, nb + 8192 + e0);
      GLD(gA1 + ko1, nb + 8192 + e1);
    }
    BAR();
    __builtin_amdgcn_s_setprio(1);
#pragma unroll
    for (int mi = 0; mi < 4; mi++)
#pragma unroll
      for (int ni = 0; ni < 4; ni++)
        acc[mi][ni] = __builtin_amdgcn_mfma_f32_16x16x32_bf16(a[mi], b[ni], acc[mi][ni], 0, 0, 0);
    __builtin_amdgcn_s_setprio(0);
    BAR();
    // ---------- phase 2 (kc0, mh1) ----------
#pragma unroll
    for (int i = 0; i < 4; i++) a[i] = *(const bf16x8*)(lds0 + base + rdA + (4 + i) * 512);
    if (t + 1 < nt) {
      GLD(gB0 + ko1, nb + 24576 + e0);
      GLD(gB1 + ko1, nb + 24576 + e1);
    }
    BAR();
    __builtin_amdgcn_s_setprio(1);
#pragma unroll
    for (int mi = 0; mi < 4; mi++)
#pragma unroll
      for (int ni = 0; ni < 4; ni++)
        acc[4 + mi][ni] =
            __builtin_amdgcn_mfma_f32_16x16x32_bf16(a[mi], b[ni], acc[4 + mi][ni], 0, 0, 0);
    __builtin_amdgcn_s_setprio(0);
    if (t + 1 < nt) {
      asm volatile("s_waitcnt vmcnt(8)" ::: "memory");  // kc1(t) landed
    } else {
      asm volatile("s_waitcnt vmcnt(0)" ::: "memory");
    }
    BAR();
    // ---------- phase 3 (kc1, mh0) ----------
#pragma unroll
    for (int i = 0; i < 4; i++) a[i] = *(const bf16x8*)(lds0 + base + 8192 + rdA + i * 512);
#pragma unroll
    for (int i = 0; i < 4; i++) b[i] = *(const bf16x8*)(lds0 + base + 24576 + rdB + i * 512);
    if (t + 2 < nt) {
      GLD(gA0 + ko2, base + e0);
      GLD(gA1 + ko2, base + e1);
    }
    BAR();
    __builtin_amdgcn_s_setprio(1);
#pragma unroll
    for (int mi = 0; mi < 4; mi++)
#pragma unroll
      for (int ni = 0; ni < 4; ni++)
        acc[mi][ni] = __builtin_amdgcn_mfma_f32_16x16x32_bf16(a[mi], b[ni], acc[mi][ni], 0, 0, 0);
    __builtin_amdgcn_s_setprio(0);
    BAR();
    // ---------- phase 4 (kc1, mh1) ----------
#pragma unroll
    for (int i = 0; i < 4; i++)
      a[i] = *(const bf16x8*)(lds0 + base + 8192 + rdA + (4 + i) * 512);
    if (t + 2 < nt) {
      GLD(gB0 + ko2, base + 16384 + e0);
      GLD(gB1 + ko2, base + 16384 + e1);
    }
    BAR();
    __builtin_amdgcn_s_setprio(1);
#pragma unroll
    for (int mi = 0; mi < 4; mi++)
#pragma unroll
      for (int ni = 0; ni < 4; ni++)
        acc[4 + mi][ni] =
            __builtin_amdgcn_mfma_f32_16x16x32_bf16(a[mi], b[ni], acc[4 + mi][ni], 0, 0, 0);
    __builtin_amdgcn_s_setprio(0);
    if (t + 2 < nt) {
      asm volatile("s_waitcnt vmcnt(8)" ::: "memory");  // kc0(t+1) landed
    } else if (t + 1 < nt) {
      asm volatile("s_waitcnt vmcnt(4)" ::: "memory");
    } else {
      asm volatile("s_waitcnt vmcnt(0)" ::: "memory");
    }
    BAR();
  }
#undef GLD

  // -------- epilogue --------
  const long zoff = (long)z * zstride;
#pragma unroll
  for (int ni = 0; ni < 4; ni++) {
    long col = bn + wc * 64 + ni * 16 + l15;
    float b4[4];
    float bcol = 0.0f;
    if (MODE == 0) {
#pragma unroll
      for (int e = 0; e < 4; e++) b4[e] = bias[(long)e * N + col];
    } else if (MODE == 2) {
      bcol = bias[col];
    }
#pragma unroll
    for (int mi = 0; mi < 8; mi++) {
#pragma unroll
      for (int r = 0; r < 4; r++) {
        long row = bm + wr * 128 + mi * 16 + l4 * 4 + r;
        float v = acc[mi][ni][r];
        if (MODE == 0) {
          float4 s4 = reinterpret_cast<const float4*>(score)[row];
          v += s4.x * b4[0] + s4.y * b4[1] + s4.z * b4[2] + s4.w * b4[3];
          outb[row * (long)N + col] = f2bf(v);
        } else if (MODE == 2) {
          float u = v + bcol;
          float zz = 0.7978845608f * (u + 0.044715f * u * u * u);
          float tt = __expf(2.0f * zz);
          float gel = u * (1.0f - 1.0f / (tt + 1.0f));
          outb[row * (long)N + col] = f2bf(gel * score[row * 4 + eidx]);
        } else {
          outb[zoff + row * (long)N + col] = f2bf(v);
        }
      }
    }
  }
}

// ---------------- flash attention (causal), writes A_pr = score_e * attn_out --------
__global__ __launch_bounds__(256) void attn_kernel(const u16* __restrict__ qkv,
                                                   const float* __restrict__ score_a,
                                                   u16* __restrict__ A_pr) {
  __shared__ __align__(16) u16 Kt[32 * 64];
  __shared__ __align__(16) u16 VT[64 * 32];
  __shared__ __align__(16) u16 Pl[4][16 * 32];
  int tid = threadIdx.x, wave = tid >> 6, lane = tid & 63;
  int l15 = lane & 15, l4 = lane >> 4;
  int qblk = blockIdx.x, bh = blockIdx.y;
  int b = bh >> 4, h = bh & 15;
  int q0 = qblk * 64 + wave * 16;
  const long LD = 3072;

  bf16x8 qf[2];
  {
    const u16* qp = qkv + (long)(b * 1024 + q0 + l15) * LD + h * 64 + l4 * 8;
    qf[0] = *(const bf16x8*)qp;
    qf[1] = *(const bf16x8*)(qp + 32);
  }
  f32x4 acc[4] = {};
  float m_run = -1e30f, l_run = 0.0f;
  int kv_end = qblk * 64 + 64;

  for (int kv0 = 0; kv0 < kv_end; kv0 += 32) {
    {
      int r = tid >> 3, c = (tid & 7) * 8;
      const u16* kp = qkv + (long)(b * 1024 + kv0 + r) * LD + 1024 + h * 64 + c;
      *(u16x8*)&Kt[r * 64 + c] = *(const u16x8*)kp;
      u16x8 vv = *(const u16x8*)(kp + 1024);
#pragma unroll
      for (int j = 0; j < 8; j++) VT[(c + j) * 32 + r] = vv[j];
    }
    __syncthreads();
    if (kv0 < q0 + 16) {
      float p[8];
      float pmax = -1e30f;
      int qg = q0 + l15;
#pragma unroll
      for (int ks = 0; ks < 2; ks++) {
        f32x4 st = {};
#pragma unroll
        for (int kc = 0; kc < 2; kc++) {
          bf16x8 kf = *(const bf16x8*)&Kt[(ks * 16 + l15) * 64 + kc * 32 + l4 * 8];
          st = __builtin_amdgcn_mfma_f32_16x16x32_bf16(kf, qf[kc], st, 0, 0, 0);
        }
#pragma unroll
        for (int r = 0; r < 4; r++) {
          int kvg = kv0 + ks * 16 + l4 * 4 + r;
          float v = st[r] * 0.125f;
          if (kvg > qg) v = -1e30f;
          p[ks * 4 + r] = v;
          pmax = fmaxf(pmax, v);
        }
      }
      pmax = fmaxf(pmax, __shfl_xor(pmax, 16, 64));
      pmax = fmaxf(pmax, __shfl_xor(pmax, 32, 64));
      float m_new = fmaxf(m_run, pmax);
      float alpha = __expf(m_run - m_new);
      float rsum = 0.f;
#pragma unroll
      for (int i = 0; i < 8; i++) {
        p[i] = __expf(p[i] - m_new);
        rsum += p[i];
      }
      rsum += __shfl_xor(rsum, 16, 64);
      rsum += __shfl_xor(rsum, 32, 64);
      l_run = l_run * alpha + rsum;
      m_run = m_new;
      float af4[4];
#pragma unroll
      for (int r = 0; r < 4; r++) af4[r] = __shfl(alpha, l4 * 4 + r, 64);
#pragma unroll
      for (int i = 0; i < 4; i++) {
#pragma unroll
        for (int r = 0; r < 4; r++) acc[i][r] *= af4[r];
      }
      u16* pw = &Pl[wave][0];
#pragma unroll
      for (int i = 0; i < 8; i++) {
        int ks = i >> 2, r = i & 3;
        pw[l15 * 32 + ks * 16 + l4 * 4 + r] = f2bf(p[i]);
      }
      bf16x8 pa = *(const bf16x8*)&pw[l15 * 32 + l4 * 8];
#pragma unroll
      for (int i = 0; i < 4; i++) {
        bf16x8 vf = *(const bf16x8*)&VT[(i * 16 + l15) * 32 + l4 * 8];
        acc[i] = __builtin_amdgcn_mfma_f32_16x16x32_bf16(pa, vf, acc[i], 0, 0, 0);
      }
    }
    __syncthreads();
  }

  float linv[4];
#pragma unroll
  for (int r = 0; r < 4; r++) {
    float lv = __shfl(l_run, l4 * 4 + r, 64);
    linv[r] = 1.0f / lv;
  }
#pragma unroll
  for (int r = 0; r < 4; r++) {
    int q = l4 * 4 + r;
    long nrow = (long)b * 1024 + q0 + q;
    float4 s4 = reinterpret_cast<const float4*>(score_a)[nrow];
    float se[4] = {s4.x, s4.y, s4.z, s4.w};
#pragma unroll
    for (int i = 0; i < 4; i++) {
      float v = acc[i][r] * linv[r];
      int d = h * 64 + i * 16 + l15;
#pragma unroll
      for (int e = 0; e < 4; e++) A_pr[nrow * 4096 + e * 1024 + d] = f2bf(se[e] * v);
    }
  }
}

// ---------------- out accumulate: FIRST: out = ybuf + bias-mix + sum_z; else out += sum_z
template <int FIRST>
__global__ __launch_bounds__(256) void accum_out(const float* __restrict__ ybuf,
                                                 const float* __restrict__ score_m,
                                                 const float* __restrict__ bp2,
                                                 const u16* __restrict__ p2t,
                                                 float* __restrict__ out) {
  int n = blockIdx.x, t = threadIdx.x;
#pragma unroll
  for (int i = 0; i < 4; i++) {
    int d = i * 256 + t;
    long idx = (long)n * D_ + d;
    float v;
    if (FIRST) {
      float4 s4 = reinterpret_cast<const float4*>(score_m)[n];
      v = ybuf[idx] + s4.x * bp2[d] + s4.y * bp2[D_ + d] + s4.z * bp2[2 * D_ + d] +
          s4.w * bp2[3 * D_ + d];
    } else {
      v = out[idx];
    }
#pragma unroll
    for (int zz = 0; zz < 4; zz++) v += bf2f(p2t[(long)zz * 4194304 + idx]);
    out[idx] = v;
  }
}

extern "C" void kernel_launch(void* const* d_in, const int* in_sizes, int n_in, void* d_out,
                              int out_size, void* d_ws, size_t ws_size, hipStream_t stream) {
  (void)in_sizes; (void)n_in; (void)out_size; (void)ws_size;
  const float* x    = (const float*)d_in[0];
  const float* Wr_a = (const float*)d_in[1];
  const float* br_a = (const float*)d_in[2];
  const float* g_a  = (const float*)d_in[3];
  const float* b_a  = (const float*)d_in[4];
  const float* Wqkv = (const float*)d_in[5];
  const float* bqkv = (const float*)d_in[6];
  const float* Wpr  = (const float*)d_in[7];
  const float* bpr  = (const float*)d_in[8];
  const float* Wr_m = (const float*)d_in[9];
  const float* br_m = (const float*)d_in[10];
  const float* g_m  = (const float*)d_in[11];
  const float* b_m  = (const float*)d_in[12];
  const float* Wfc  = (const float*)d_in[13];
  const float* bfc  = (const float*)d_in[14];
  const float* Wp2  = (const float*)d_in[15];
  const float* bp2  = (const float*)d_in[16];
  float* out = (float*)d_out;

  // ---- workspace: 136.25 MB, stream-ordered region reuse ----
  char* ws = (char*)d_ws;
  const size_t oW = 0;                  // 24MB: wt_qkv -> wt_pr -> {wt_fce, wt_p2e}
  const size_t oA = 25165824;           // 32MB: A_a -> prt(bf16) -> A_fc
  const size_t oQ = oA + 33554432;      // 32MB: qkvb -> p2t(bf16)
  const size_t oP = oQ + 33554432;      // 32MB: A_pr -> inter
  const size_t oY = oP + 33554432;      // 16MB: ybuf
  const size_t oS = oY + 16777216;      // scores
  u16* wt_qkv  = (u16*)(ws + oW);
  u16* wt_pr   = (u16*)(ws + oW);
  u16* wt_fce  = (u16*)(ws + oW);
  u16* wt_p2e  = (u16*)(ws + oW + (size_t)8 * 1024 * 1024);
  u16* A_a     = (u16*)(ws + oA);
  u16* prt     = (u16*)(ws + oA);
  u16* A_fc    = (u16*)(ws + oA);
  u16* qkvb    = (u16*)(ws + oQ);
  u16* p2t     = (u16*)(ws + oQ);
  u16* A_pr    = (u16*)(ws + oP);
  u16* inter   = (u16*)(ws + oP);
  float* ybuf  = (float*)(ws + oY);
  float* score_a = (float*)(ws + oS);
  float* score_m = (float*)(ws + oS + 65536);

  dim3 tb(32, 8);
  // ---- attention half ----
  tcvt<<<dim3(3072 / 32, 4096 / 32), tb, 0, stream>>>(Wqkv, wt_qkv, 4096, 3072);
  ln_router_expand<0><<<N_, 256, 0, stream>>>(x, Wr_a, br_a, g_a, b_a, score_a, A_a,
                                              (long)1024, (long)4096, 1,
                                              nullptr, nullptr, nullptr, nullptr);
  g8<0><<<dim3(3072 / 256, 4096 / 256, 1), 512, 0, stream>>>(
      A_a, wt_qkv, 4096, 3072, 4096, score_a, bqkv, qkvb, 0, 0L);
  attn_kernel<<<dim3(S_ / 64, B_ * H_), 256, 0, stream>>>(qkvb, score_a, A_pr);
  tcvt<<<dim3(1024 / 32, 4096 / 32), tb, 0, stream>>>(Wpr, wt_pr, 4096, 1024);
  g8<4><<<dim3(1024 / 256, 4096 / 256, 4), 512, 0, stream>>>(
      A_pr, wt_pr, 4096, 1024, 1024, nullptr, nullptr, prt, 0, (long)4096 * 1024);

  // ---- MLP half (ln fused with y-reconstruction) ----
  ln_router_expand<1><<<N_, 256, 0, stream>>>(x, Wr_m, br_m, g_m, b_m,
                                              score_m, A_fc, (long)N_ * 1024, (long)1024, 0,
                                              score_a, bpr, prt, ybuf);
  for (int e = 0; e < 4; e++) {
    tcvt<<<dim3(4096 / 32, 1024 / 32), tb, 0, stream>>>(
        Wfc + (size_t)e * 1024 * 4096, wt_fce, 1024, 4096);
    g8<2><<<dim3(4096 / 256, 4096 / 256, 1), 512, 0, stream>>>(
        A_fc + (size_t)e * N_ * 1024, wt_fce, 1024, 4096, 1024, score_m,
        bfc + e * 4096, inter, e, 0L);
    tcvt<<<dim3(1024 / 32, 4096 / 32), tb, 0, stream>>>(
        Wp2 + (size_t)e * 4096 * 1024, wt_p2e, 4096, 1024);
    g8<4><<<dim3(1024 / 256, 4096 / 256, 4), 512, 0, stream>>>(
        inter, wt_p2e, 4096, 1024, 1024, nullptr, nullptr, p2t, 0, (long)4096 * 1024);
    if (e == 0) {
      accum_out<1><<<N_, 256, 0, stream>>>(ybuf, score_m, bp2, p2t, out);
    } else {
      accum_out<0><<<N_, 256, 0, stream>>>(nullptr, nullptr, nullptr, p2t, out);
    }
  }
}

// Round 7
// 800.298 us; speedup vs baseline: 1.3518x; 1.0049x over previous
//
#include <hip/hip_runtime.h>
#include <hip/hip_bf16.h>

typedef __bf16 bf16x8 __attribute__((ext_vector_type(8)));
typedef float f32x4 __attribute__((ext_vector_type(4)));
typedef unsigned short u16;
typedef u16 u16x8 __attribute__((ext_vector_type(8)));
typedef u16 u16x4 __attribute__((ext_vector_type(4)));

#define B_ 4
#define S_ 1024
#define D_ 1024
#define E_ 4
#define H_ 16
#define FF_ 4096
#define N_ 4096

__device__ __forceinline__ u16 f2bf(float f) {
  __hip_bfloat16 h = __float2bfloat16(f);
  return *reinterpret_cast<u16*>(&h);
}
__device__ __forceinline__ float bf2f(u16 v) {
  return __uint_as_float(((unsigned)v) << 16);
}

#define BAR()                         \
  {                                   \
    asm volatile("" ::: "memory");    \
    __builtin_amdgcn_s_barrier();     \
    asm volatile("" ::: "memory");    \
  }

// ---------------- transpose + f32->bf16 convert: dst[c][r] = src[r][c] ----------------
__global__ __launch_bounds__(256) void tcvt(const float* __restrict__ src,
                                            u16* __restrict__ dst, int R, int C) {
  __shared__ float t[32][33];
  int r0 = blockIdx.y * 32, c0 = blockIdx.x * 32;
  int tx = threadIdx.x, ty = threadIdx.y;  // 32 x 8
#pragma unroll
  for (int i = 0; i < 4; i++)
    t[ty + i * 8][tx] = src[(long)(r0 + ty + i * 8) * C + c0 + tx];
  __syncthreads();
#pragma unroll
  for (int i = 0; i < 4; i++)
    dst[(long)(c0 + ty + i * 8) * R + r0 + tx] = f2bf(t[tx][ty + i * 8]);
}

// ---------------- LN + router softmax + per-expert expand (vectorized x4) ------------
// YMODE=0: row = X[n]. YMODE=1: row = X[n] + sum_e score_a[e]*bpr[e] + sum_z prt_z;
// also writes reconstructed row to ybuf. Thread t owns d0 = t*4 (contiguous).
template <int YMODE>
__global__ __launch_bounds__(256) void ln_router_expand(
    const float* __restrict__ X, const float* __restrict__ Wr, const float* __restrict__ br,
    const float* __restrict__ g, const float* __restrict__ bb,
    float* __restrict__ score_out, u16* __restrict__ Aout,
    long stride_e, long stride_n, int scale_flag,
    const float* __restrict__ score_a, const float* __restrict__ bpr,
    const u16* __restrict__ prt, float* __restrict__ ybuf) {
  int n = blockIdx.x, t = threadIdx.x;
  int lane = t & 63, wave = t >> 6;
  int d0 = t * 4;
  const float* xr = X + (long)n * D_;
  float4 xv = *reinterpret_cast<const float4*>(&xr[d0]);
  if (YMODE) {
    float4 sa4 = reinterpret_cast<const float4*>(score_a)[n];
    float4 b0 = *reinterpret_cast<const float4*>(&bpr[d0]);
    float4 b1 = *reinterpret_cast<const float4*>(&bpr[D_ + d0]);
    float4 b2 = *reinterpret_cast<const float4*>(&bpr[2 * D_ + d0]);
    float4 b3 = *reinterpret_cast<const float4*>(&bpr[3 * D_ + d0]);
    xv.x += sa4.x * b0.x + sa4.y * b1.x + sa4.z * b2.x + sa4.w * b3.x;
    xv.y += sa4.x * b0.y + sa4.y * b1.y + sa4.z * b2.y + sa4.w * b3.y;
    xv.z += sa4.x * b0.z + sa4.y * b1.z + sa4.z * b2.z + sa4.w * b3.z;
    xv.w += sa4.x * b0.w + sa4.y * b1.w + sa4.z * b2.w + sa4.w * b3.w;
    long idx = (long)n * D_ + d0;
#pragma unroll
    for (int zz = 0; zz < 4; zz++) {
      u16x4 pv = *reinterpret_cast<const u16x4*>(&prt[(long)zz * 4194304 + idx]);
      xv.x += bf2f(pv[0]); xv.y += bf2f(pv[1]); xv.z += bf2f(pv[2]); xv.w += bf2f(pv[3]);
    }
    *reinterpret_cast<float4*>(&ybuf[idx]) = xv;
  }
  float vals[6];
  vals[0] = xv.x + xv.y + xv.z + xv.w;
  vals[1] = xv.x * xv.x + xv.y * xv.y + xv.z * xv.z + xv.w * xv.w;
  {
    float4 w0 = reinterpret_cast<const float4*>(Wr)[d0];
    float4 w1 = reinterpret_cast<const float4*>(Wr)[d0 + 1];
    float4 w2 = reinterpret_cast<const float4*>(Wr)[d0 + 2];
    float4 w3 = reinterpret_cast<const float4*>(Wr)[d0 + 3];
    vals[2] = xv.x * w0.x + xv.y * w1.x + xv.z * w2.x + xv.w * w3.x;
    vals[3] = xv.x * w0.y + xv.y * w1.y + xv.z * w2.y + xv.w * w3.y;
    vals[4] = xv.x * w0.z + xv.y * w1.z + xv.z * w2.z + xv.w * w3.z;
    vals[5] = xv.x * w0.w + xv.y * w1.w + xv.z * w2.w + xv.w * w3.w;
  }
#pragma unroll
  for (int o = 1; o < 64; o <<= 1) {
#pragma unroll
    for (int j = 0; j < 6; j++) vals[j] += __shfl_xor(vals[j], o, 64);
  }
  __shared__ float red[4][6];
  if (lane == 0) {
#pragma unroll
    for (int j = 0; j < 6; j++) red[wave][j] = vals[j];
  }
  __syncthreads();
  float tot[6];
#pragma unroll
  for (int j = 0; j < 6; j++) tot[j] = red[0][j] + red[1][j] + red[2][j] + red[3][j];
  float mean = tot[0] * (1.0f / D_);
  float var = tot[1] * (1.0f / D_) - mean * mean;
  float rstd = rsqrtf(var + 1e-5f);
  float lg0 = tot[2] + br[0], lg1 = tot[3] + br[1], lg2 = tot[4] + br[2], lg3 = tot[5] + br[3];
  float mx = fmaxf(fmaxf(lg0, lg1), fmaxf(lg2, lg3));
  float e0 = __expf(lg0 - mx), e1 = __expf(lg1 - mx), e2 = __expf(lg2 - mx), e3 = __expf(lg3 - mx);
  float inv = 1.0f / (e0 + e1 + e2 + e3);
  float sc[4] = {e0 * inv, e1 * inv, e2 * inv, e3 * inv};
  if (t == 0) {
    float4 s4 = make_float4(sc[0], sc[1], sc[2], sc[3]);
    *reinterpret_cast<float4*>(&score_out[(long)n * 4]) = s4;
  }
  float4 hn;
  hn.x = (xv.x - mean) * rstd; hn.y = (xv.y - mean) * rstd;
  hn.z = (xv.z - mean) * rstd; hn.w = (xv.w - mean) * rstd;
#pragma unroll
  for (int e = 0; e < 4; e++) {
    float4 ge = *reinterpret_cast<const float4*>(&g[e * D_ + d0]);
    float4 be = *reinterpret_cast<const float4*>(&bb[e * D_ + d0]);
    float s = scale_flag ? sc[e] : 1.0f;
    u16x4 o;
    o[0] = f2bf((hn.x * ge.x + be.x) * s);
    o[1] = f2bf((hn.y * ge.y + be.y) * s);
    o[2] = f2bf((hn.z * ge.z + be.z) * s);
    o[3] = f2bf((hn.w * ge.w + be.w) * s);
    *reinterpret_cast<u16x4*>(&Aout[(long)e * stride_e + (long)n * stride_n + d0]) = o;
  }
}

// ======== 8-wave 256x256 GEMM, 2 consolidated phases per K-tile, deep-pipelined ======
// LDS regions (u16 idx): buf(t&1)*32768 + {A-kc0:0, A-kc1:8192, B-kc0:16384, B-kc1:24576}
// Phase A: read kc0 frags (a[8]+b[4]), stage A-kc1(t+1)+B-kc1(t+1) (4 GLD), BAR,
//          32 MFMA, wait W_A, BAR.
// Phase B: read kc1 frags, stage A-kc0(t+2)+B-kc0(t+2), BAR, 32 MFMA, wait W_B, BAR.
// W_A=(t+1<nt)?8:0 ; W_B=(t+2<nt)?8:((t+1<nt)?4:0). Queue hovers 8-12, never drains.
// XCD-chunked bijective block swizzle over flat grid (totals % 8 == 0).
// MODE 0: outb = bf16(acc + sum_e score[row][e]*bias[e*N+col])       (qkv)
// MODE 2: outb = bf16(score[row*4+eidx] * gelu(acc + bias[col]))     (fc)
// MODE 4: outb[z*zstride + ...] = bf16(acc)                          (splitK partials)
template <int MODE>
__global__ __launch_bounds__(512, 2) void g8(
    const u16* __restrict__ A, const u16* __restrict__ Bt, int K, int N, int kslice,
    const float* __restrict__ score, const float* __restrict__ bias,
    u16* __restrict__ outb, int eidx, long zstride) {
  __shared__ __align__(16) u16 lds0[65536];  // 128 KiB
  const int tid = threadIdx.x;
  const int w = tid >> 6, lane = tid & 63;
  const int l15 = lane & 15, l4 = lane >> 4;
  const int wr = w >> 2, wc = w & 3;

  // ---- XCD-aware swizzle ----
  const int gx = gridDim.x, gy = gridDim.y;
  const int total = gx * gy * gridDim.z;
  const int flat = blockIdx.x + gx * (blockIdx.y + gy * blockIdx.z);
  const int cpx = total >> 3;
  const int nf = (flat & 7) * cpx + (flat >> 3);
  const int bxi = nf % gx;
  const int tmp = nf / gx;
  const int byi = tmp % gy;
  const int z = tmp / gy;

  const long bm = (long)byi * 256, bn = (long)bxi * 256;
  const long k0 = (long)z * kslice;
  const int nt = kslice >> 6;

  // staging geometry
  const int cp = lane & 3;
  const int sr0 = w * 32 + (lane >> 2);
  const int sr1 = sr0 + 16;
  const int cl0 = cp ^ ((sr0 >> 1) & 3);
  const int cl1 = cp ^ ((sr1 >> 1) & 3);
  const u16* gA0 = A + (bm + sr0) * (long)K + k0 + cl0 * 8;
  const u16* gA1 = A + (bm + sr1) * (long)K + k0 + cl1 * 8;
  const u16* gB0 = Bt + (bn + sr0) * (long)K + k0 + cl0 * 8;
  const u16* gB1 = Bt + (bn + sr1) * (long)K + k0 + cl1 * 8;
  const int e0 = w * 1024;
  const int e1 = w * 1024 + 512;

  // frag-read bases (u16 units within a region)
  const int chA = l4 ^ ((l15 >> 1) & 3);
  const int rdA = (wr * 128 + l15) * 32 + chA * 8;  // + mi*512
  const int rdB = (wc * 64 + l15) * 32 + chA * 8;   // + ni*512

#define GLD(gsrc, ldsoff)                                                              \
  __builtin_amdgcn_global_load_lds(                                                    \
      (const __attribute__((address_space(1))) void*)(gsrc),                           \
      (__attribute__((address_space(3))) void*)(lds0 + (ldsoff)), 16, 0, 0)

  // -------- prologue: tile0 kc0, kc1; tile1 kc0 --------
  GLD(gA0, 0 + e0);
  GLD(gA1, 0 + e1);
  GLD(gB0, 16384 + e0);
  GLD(gB1, 16384 + e1);
  GLD(gA0 + 32, 8192 + e0);
  GLD(gA1 + 32, 8192 + e1);
  GLD(gB0 + 32, 24576 + e0);
  GLD(gB1 + 32, 24576 + e1);
  if (nt > 1) {
    GLD(gA0 + 64, 32768 + e0);
    GLD(gA1 + 64, 32768 + e1);
    GLD(gB0 + 64, 32768 + 16384 + e0);
    GLD(gB1 + 64, 32768 + 16384 + e1);
    asm volatile("s_waitcnt vmcnt(8)" ::: "memory");
  } else {
    asm volatile("s_waitcnt vmcnt(4)" ::: "memory");
  }
  BAR();

  f32x4 acc[8][4] = {};
  bf16x8 a[8], b[4];

  for (int t = 0; t < nt; ++t) {
    const int base = (t & 1) * 32768;
    const int nb = base ^ 32768;
    const long ko1 = (long)(t + 1) * 64 + 32;
    const long ko2 = (long)(t + 2) * 64;
    // ---------- phase A (kc0): 12 ds_read, stage kc1(t+1), 32 MFMA ----------
#pragma unroll
    for (int i = 0; i < 8; i++) a[i] = *(const bf16x8*)(lds0 + base + rdA + i * 512);
#pragma unroll
    for (int i = 0; i < 4; i++) b[i] = *(const bf16x8*)(lds0 + base + 16384 + rdB + i * 512);
    if (t + 1 < nt) {
      GLD(gA0 + ko1, nb + 8192 + e0);
      GLD(gA1 + ko1, nb + 8192 + e1);
      GLD(gB0 + ko1, nb + 24576 + e0);
      GLD(gB1 + ko1, nb + 24576 + e1);
    }
    BAR();
    __builtin_amdgcn_s_setprio(1);
#pragma unroll
    for (int mi = 0; mi < 8; mi++)
#pragma unroll
      for (int ni = 0; ni < 4; ni++)
        acc[mi][ni] = __builtin_amdgcn_mfma_f32_16x16x32_bf16(a[mi], b[ni], acc[mi][ni], 0, 0, 0);
    __builtin_amdgcn_s_setprio(0);
    if (t + 1 < nt) {
      asm volatile("s_waitcnt vmcnt(8)" ::: "memory");  // forces kc1(t) resident
    } else {
      asm volatile("s_waitcnt vmcnt(0)" ::: "memory");
    }
    BAR();
    // ---------- phase B (kc1): 12 ds_read, stage kc0(t+2), 32 MFMA ----------
#pragma unroll
    for (int i = 0; i < 8; i++) a[i] = *(const bf16x8*)(lds0 + base + 8192 + rdA + i * 512);
#pragma unroll
    for (int i = 0; i < 4; i++) b[i] = *(const bf16x8*)(lds0 + base + 24576 + rdB + i * 512);
    if (t + 2 < nt) {
      GLD(gA0 + ko2, base + e0);
      GLD(gA1 + ko2, base + e1);
      GLD(gB0 + ko2, base + 16384 + e0);
      GLD(gB1 + ko2, base + 16384 + e1);
    }
    BAR();
    __builtin_amdgcn_s_setprio(1);
#pragma unroll
    for (int mi = 0; mi < 8; mi++)
#pragma unroll
      for (int ni = 0; ni < 4; ni++)
        acc[mi][ni] = __builtin_amdgcn_mfma_f32_16x16x32_bf16(a[mi], b[ni], acc[mi][ni], 0, 0, 0);
    __builtin_amdgcn_s_setprio(0);
    if (t + 2 < nt) {
      asm volatile("s_waitcnt vmcnt(8)" ::: "memory");  // forces kc0(t+1) resident
    } else if (t + 1 < nt) {
      asm volatile("s_waitcnt vmcnt(4)" ::: "memory");
    } else {
      asm volatile("s_waitcnt vmcnt(0)" ::: "memory");
    }
    BAR();
  }
#undef GLD

  // -------- epilogue --------
  const long zoff = (long)z * zstride;
#pragma unroll
  for (int ni = 0; ni < 4; ni++) {
    long col = bn + wc * 64 + ni * 16 + l15;
    float b4[4];
    float bcol = 0.0f;
    if (MODE == 0) {
#pragma unroll
      for (int e = 0; e < 4; e++) b4[e] = bias[(long)e * N + col];
    } else if (MODE == 2) {
      bcol = bias[col];
    }
#pragma unroll
    for (int mi = 0; mi < 8; mi++) {
#pragma unroll
      for (int r = 0; r < 4; r++) {
        long row = bm + wr * 128 + mi * 16 + l4 * 4 + r;
        float v = acc[mi][ni][r];
        if (MODE == 0) {
          float4 s4 = reinterpret_cast<const float4*>(score)[row];
          v += s4.x * b4[0] + s4.y * b4[1] + s4.z * b4[2] + s4.w * b4[3];
          outb[row * (long)N + col] = f2bf(v);
        } else if (MODE == 2) {
          float u = v + bcol;
          float zz = 0.7978845608f * (u + 0.044715f * u * u * u);
          float tt = __expf(2.0f * zz);
          float gel = u * (1.0f - 1.0f / (tt + 1.0f));
          outb[row * (long)N + col] = f2bf(gel * score[row * 4 + eidx]);
        } else {
          outb[zoff + row * (long)N + col] = f2bf(v);
        }
      }
    }
  }
}

// ---------------- flash attention (causal), writes A_pr = score_e * attn_out --------
__global__ __launch_bounds__(256) void attn_kernel(const u16* __restrict__ qkv,
                                                   const float* __restrict__ score_a,
                                                   u16* __restrict__ A_pr) {
  __shared__ __align__(16) u16 Kt[32 * 64];
  __shared__ __align__(16) u16 VT[64 * 32];
  __shared__ __align__(16) u16 Pl[4][16 * 32];
  int tid = threadIdx.x, wave = tid >> 6, lane = tid & 63;
  int l15 = lane & 15, l4 = lane >> 4;
  int qblk = blockIdx.x, bh = blockIdx.y;
  int b = bh >> 4, h = bh & 15;
  int q0 = qblk * 64 + wave * 16;
  const long LD = 3072;

  bf16x8 qf[2];
  {
    const u16* qp = qkv + (long)(b * 1024 + q0 + l15) * LD + h * 64 + l4 * 8;
    qf[0] = *(const bf16x8*)qp;
    qf[1] = *(const bf16x8*)(qp + 32);
  }
  f32x4 acc[4] = {};
  float m_run = -1e30f, l_run = 0.0f;
  int kv_end = qblk * 64 + 64;

  for (int kv0 = 0; kv0 < kv_end; kv0 += 32) {
    {
      int r = tid >> 3, c = (tid & 7) * 8;
      const u16* kp = qkv + (long)(b * 1024 + kv0 + r) * LD + 1024 + h * 64 + c;
      *(u16x8*)&Kt[r * 64 + c] = *(const u16x8*)kp;
      u16x8 vv = *(const u16x8*)(kp + 1024);
#pragma unroll
      for (int j = 0; j < 8; j++) VT[(c + j) * 32 + r] = vv[j];
    }
    __syncthreads();
    if (kv0 < q0 + 16) {
      float p[8];
      float pmax = -1e30f;
      int qg = q0 + l15;
#pragma unroll
      for (int ks = 0; ks < 2; ks++) {
        f32x4 st = {};
#pragma unroll
        for (int kc = 0; kc < 2; kc++) {
          bf16x8 kf = *(const bf16x8*)&Kt[(ks * 16 + l15) * 64 + kc * 32 + l4 * 8];
          st = __builtin_amdgcn_mfma_f32_16x16x32_bf16(kf, qf[kc], st, 0, 0, 0);
        }
#pragma unroll
        for (int r = 0; r < 4; r++) {
          int kvg = kv0 + ks * 16 + l4 * 4 + r;
          float v = st[r] * 0.125f;
          if (kvg > qg) v = -1e30f;
          p[ks * 4 + r] = v;
          pmax = fmaxf(pmax, v);
        }
      }
      pmax = fmaxf(pmax, __shfl_xor(pmax, 16, 64));
      pmax = fmaxf(pmax, __shfl_xor(pmax, 32, 64));
      float m_new = fmaxf(m_run, pmax);
      float alpha = __expf(m_run - m_new);
      float rsum = 0.f;
#pragma unroll
      for (int i = 0; i < 8; i++) {
        p[i] = __expf(p[i] - m_new);
        rsum += p[i];
      }
      rsum += __shfl_xor(rsum, 16, 64);
      rsum += __shfl_xor(rsum, 32, 64);
      l_run = l_run * alpha + rsum;
      m_run = m_new;
      float af4[4];
#pragma unroll
      for (int r = 0; r < 4; r++) af4[r] = __shfl(alpha, l4 * 4 + r, 64);
#pragma unroll
      for (int i = 0; i < 4; i++) {
#pragma unroll
        for (int r = 0; r < 4; r++) acc[i][r] *= af4[r];
      }
      u16* pw = &Pl[wave][0];
#pragma unroll
      for (int i = 0; i < 8; i++) {
        int ks = i >> 2, r = i & 3;
        pw[l15 * 32 + ks * 16 + l4 * 4 + r] = f2bf(p[i]);
      }
      bf16x8 pa = *(const bf16x8*)&pw[l15 * 32 + l4 * 8];
#pragma unroll
      for (int i = 0; i < 4; i++) {
        bf16x8 vf = *(const bf16x8*)&VT[(i * 16 + l15) * 32 + l4 * 8];
        acc[i] = __builtin_amdgcn_mfma_f32_16x16x32_bf16(pa, vf, acc[i], 0, 0, 0);
      }
    }
    __syncthreads();
  }

  float linv[4];
#pragma unroll
  for (int r = 0; r < 4; r++) {
    float lv = __shfl(l_run, l4 * 4 + r, 64);
    linv[r] = 1.0f / lv;
  }
#pragma unroll
  for (int r = 0; r < 4; r++) {
    int q = l4 * 4 + r;
    long nrow = (long)b * 1024 + q0 + q;
    float4 s4 = reinterpret_cast<const float4*>(score_a)[nrow];
    float se[4] = {s4.x, s4.y, s4.z, s4.w};
#pragma unroll
    for (int i = 0; i < 4; i++) {
      float v = acc[i][r] * linv[r];
      int d = h * 64 + i * 16 + l15;
#pragma unroll
      for (int e = 0; e < 4; e++) A_pr[nrow * 4096 + e * 1024 + d] = f2bf(se[e] * v);
    }
  }
}

// -------- out accumulate (vectorized x4): FIRST: out = ybuf + bias-mix + sum_z; else +=
template <int FIRST>
__global__ __launch_bounds__(256) void accum_out(const float* __restrict__ ybuf,
                                                 const float* __restrict__ score_m,
                                                 const float* __restrict__ bp2,
                                                 const u16* __restrict__ p2t,
                                                 float* __restrict__ out) {
  int n = blockIdx.x, t = threadIdx.x;
  int d0 = t * 4;
  long idx = (long)n * D_ + d0;
  float4 v;
  if (FIRST) {
    float4 s4 = reinterpret_cast<const float4*>(score_m)[n];
    float4 b0 = *reinterpret_cast<const float4*>(&bp2[d0]);
    float4 b1 = *reinterpret_cast<const float4*>(&bp2[D_ + d0]);
    float4 b2 = *reinterpret_cast<const float4*>(&bp2[2 * D_ + d0]);
    float4 b3 = *reinterpret_cast<const float4*>(&bp2[3 * D_ + d0]);
    v = *reinterpret_cast<const float4*>(&ybuf[idx]);
    v.x += s4.x * b0.x + s4.y * b1.x + s4.z * b2.x + s4.w * b3.x;
    v.y += s4.x * b0.y + s4.y * b1.y + s4.z * b2.y + s4.w * b3.y;
    v.z += s4.x * b0.z + s4.y * b1.z + s4.z * b2.z + s4.w * b3.z;
    v.w += s4.x * b0.w + s4.y * b1.w + s4.z * b2.w + s4.w * b3.w;
  } else {
    v = *reinterpret_cast<const float4*>(&out[idx]);
  }
#pragma unroll
  for (int zz = 0; zz < 4; zz++) {
    u16x4 pv = *reinterpret_cast<const u16x4*>(&p2t[(long)zz * 4194304 + idx]);
    v.x += bf2f(pv[0]); v.y += bf2f(pv[1]); v.z += bf2f(pv[2]); v.w += bf2f(pv[3]);
  }
  *reinterpret_cast<float4*>(&out[idx]) = v;
}

extern "C" void kernel_launch(void* const* d_in, const int* in_sizes, int n_in, void* d_out,
                              int out_size, void* d_ws, size_t ws_size, hipStream_t stream) {
  (void)in_sizes; (void)n_in; (void)out_size; (void)ws_size;
  const float* x    = (const float*)d_in[0];
  const float* Wr_a = (const float*)d_in[1];
  const float* br_a = (const float*)d_in[2];
  const float* g_a  = (const float*)d_in[3];
  const float* b_a  = (const float*)d_in[4];
  const float* Wqkv = (const float*)d_in[5];
  const float* bqkv = (const float*)d_in[6];
  const float* Wpr  = (const float*)d_in[7];
  const float* bpr  = (const float*)d_in[8];
  const float* Wr_m = (const float*)d_in[9];
  const float* br_m = (const float*)d_in[10];
  const float* g_m  = (const float*)d_in[11];
  const float* b_m  = (const float*)d_in[12];
  const float* Wfc  = (const float*)d_in[13];
  const float* bfc  = (const float*)d_in[14];
  const float* Wp2  = (const float*)d_in[15];
  const float* bp2  = (const float*)d_in[16];
  float* out = (float*)d_out;

  // ---- workspace: 136.25 MB, stream-ordered region reuse ----
  char* ws = (char*)d_ws;
  const size_t oW = 0;                  // 24MB: wt_qkv -> wt_pr -> {wt_fce, wt_p2e}
  const size_t oA = 25165824;           // 32MB: A_a -> prt(bf16) -> A_fc
  const size_t oQ = oA + 33554432;      // 32MB: qkvb -> p2t(bf16)
  const size_t oP = oQ + 33554432;      // 32MB: A_pr -> inter
  const size_t oY = oP + 33554432;      // 16MB: ybuf
  const size_t oS = oY + 16777216;      // scores
  u16* wt_qkv  = (u16*)(ws + oW);
  u16* wt_pr   = (u16*)(ws + oW);
  u16* wt_fce  = (u16*)(ws + oW);
  u16* wt_p2e  = (u16*)(ws + oW + (size_t)8 * 1024 * 1024);
  u16* A_a     = (u16*)(ws + oA);
  u16* prt     = (u16*)(ws + oA);
  u16* A_fc    = (u16*)(ws + oA);
  u16* qkvb    = (u16*)(ws + oQ);
  u16* p2t     = (u16*)(ws + oQ);
  u16* A_pr    = (u16*)(ws + oP);
  u16* inter   = (u16*)(ws + oP);
  float* ybuf  = (float*)(ws + oY);
  float* score_a = (float*)(ws + oS);
  float* score_m = (float*)(ws + oS + 65536);

  dim3 tb(32, 8);
  // ---- attention half ----
  tcvt<<<dim3(3072 / 32, 4096 / 32), tb, 0, stream>>>(Wqkv, wt_qkv, 4096, 3072);
  ln_router_expand<0><<<N_, 256, 0, stream>>>(x, Wr_a, br_a, g_a, b_a, score_a, A_a,
                                              (long)1024, (long)4096, 1,
                                              nullptr, nullptr, nullptr, nullptr);
  g8<0><<<dim3(3072 / 256, 4096 / 256, 1), 512, 0, stream>>>(
      A_a, wt_qkv, 4096, 3072, 4096, score_a, bqkv, qkvb, 0, 0L);
  attn_kernel<<<dim3(S_ / 64, B_ * H_), 256, 0, stream>>>(qkvb, score_a, A_pr);
  tcvt<<<dim3(1024 / 32, 4096 / 32), tb, 0, stream>>>(Wpr, wt_pr, 4096, 1024);
  g8<4><<<dim3(1024 / 256, 4096 / 256, 4), 512, 0, stream>>>(
      A_pr, wt_pr, 4096, 1024, 1024, nullptr, nullptr, prt, 0, (long)4096 * 1024);

  // ---- MLP half (ln fused with y-reconstruction) ----
  ln_router_expand<1><<<N_, 256, 0, stream>>>(x, Wr_m, br_m, g_m, b_m,
                                              score_m, A_fc, (long)N_ * 1024, (long)1024, 0,
                                              score_a, bpr, prt, ybuf);
  for (int e = 0; e < 4; e++) {
    tcvt<<<dim3(4096 / 32, 1024 / 32), tb, 0, stream>>>(
        Wfc + (size_t)e * 1024 * 4096, wt_fce, 1024, 4096);
    g8<2><<<dim3(4096 / 256, 4096 / 256, 1), 512, 0, stream>>>(
        A_fc + (size_t)e * N_ * 1024, wt_fce, 1024, 4096, 1024, score_m,
        bfc + e * 4096, inter, e, 0L);
    tcvt<<<dim3(1024 / 32, 4096 / 32), tb, 0, stream>>>(
        Wp2 + (size_t)e * 4096 * 1024, wt_p2e, 4096, 1024);
    g8<4><<<dim3(1024 / 256, 4096 / 256, 4), 512, 0, stream>>>(
        inter, wt_p2e, 4096, 1024, 1024, nullptr, nullptr, p2t, 0, (long)4096 * 1024);
    if (e == 0) {
      accum_out<1><<<N_, 256, 0, stream>>>(ybuf, score_m, bp2, p2t, out);
    } else {
      accum_out<0><<<N_, 256, 0, stream>>>(nullptr, nullptr, nullptr, p2t, out);
    }
  }
}

// Round 8
// 789.388 us; speedup vs baseline: 1.3704x; 1.0138x over previous
//
#include <hip/hip_runtime.h>
#include <hip/hip_bf16.h>

typedef __bf16 bf16x8 __attribute__((ext_vector_type(8)));
typedef float f32x4 __attribute__((ext_vector_type(4)));
typedef unsigned short u16;
typedef u16 u16x8 __attribute__((ext_vector_type(8)));
typedef u16 u16x4 __attribute__((ext_vector_type(4)));

#define B_ 4
#define S_ 1024
#define D_ 1024
#define E_ 4
#define H_ 16
#define FF_ 4096
#define N_ 4096

__device__ __forceinline__ u16 f2bf(float f) {
  __hip_bfloat16 h = __float2bfloat16(f);
  return *reinterpret_cast<u16*>(&h);
}
__device__ __forceinline__ float bf2f(u16 v) {
  return __uint_as_float(((unsigned)v) << 16);
}

#define BAR()                         \
  {                                   \
    asm volatile("" ::: "memory");    \
    __builtin_amdgcn_s_barrier();     \
    asm volatile("" ::: "memory");    \
  }

// ---------------- transpose + f32->bf16 convert: dst[c][r] = src[r][c] ----------------
__global__ __launch_bounds__(256) void tcvt(const float* __restrict__ src,
                                            u16* __restrict__ dst, int R, int C) {
  __shared__ float t[32][33];
  int r0 = blockIdx.y * 32, c0 = blockIdx.x * 32;
  int tx = threadIdx.x, ty = threadIdx.y;  // 32 x 8
#pragma unroll
  for (int i = 0; i < 4; i++)
    t[ty + i * 8][tx] = src[(long)(r0 + ty + i * 8) * C + c0 + tx];
  __syncthreads();
#pragma unroll
  for (int i = 0; i < 4; i++)
    dst[(long)(c0 + ty + i * 8) * R + r0 + tx] = f2bf(t[tx][ty + i * 8]);
}

// ---------------- LN + router softmax + per-expert expand (vectorized x4) ------------
template <int YMODE>
__global__ __launch_bounds__(256) void ln_router_expand(
    const float* __restrict__ X, const float* __restrict__ Wr, const float* __restrict__ br,
    const float* __restrict__ g, const float* __restrict__ bb,
    float* __restrict__ score_out, u16* __restrict__ Aout,
    long stride_e, long stride_n, int scale_flag,
    const float* __restrict__ score_a, const float* __restrict__ bpr,
    const u16* __restrict__ prt, float* __restrict__ ybuf) {
  int n = blockIdx.x, t = threadIdx.x;
  int lane = t & 63, wave = t >> 6;
  int d0 = t * 4;
  const float* xr = X + (long)n * D_;
  float4 xv = *reinterpret_cast<const float4*>(&xr[d0]);
  if (YMODE) {
    float4 sa4 = reinterpret_cast<const float4*>(score_a)[n];
    float4 b0 = *reinterpret_cast<const float4*>(&bpr[d0]);
    float4 b1 = *reinterpret_cast<const float4*>(&bpr[D_ + d0]);
    float4 b2 = *reinterpret_cast<const float4*>(&bpr[2 * D_ + d0]);
    float4 b3 = *reinterpret_cast<const float4*>(&bpr[3 * D_ + d0]);
    xv.x += sa4.x * b0.x + sa4.y * b1.x + sa4.z * b2.x + sa4.w * b3.x;
    xv.y += sa4.x * b0.y + sa4.y * b1.y + sa4.z * b2.y + sa4.w * b3.y;
    xv.z += sa4.x * b0.z + sa4.y * b1.z + sa4.z * b2.z + sa4.w * b3.z;
    xv.w += sa4.x * b0.w + sa4.y * b1.w + sa4.z * b2.w + sa4.w * b3.w;
    long idx = (long)n * D_ + d0;
#pragma unroll
    for (int zz = 0; zz < 4; zz++) {
      u16x4 pv = *reinterpret_cast<const u16x4*>(&prt[(long)zz * 4194304 + idx]);
      xv.x += bf2f(pv[0]); xv.y += bf2f(pv[1]); xv.z += bf2f(pv[2]); xv.w += bf2f(pv[3]);
    }
    *reinterpret_cast<float4*>(&ybuf[idx]) = xv;
  }
  float vals[6];
  vals[0] = xv.x + xv.y + xv.z + xv.w;
  vals[1] = xv.x * xv.x + xv.y * xv.y + xv.z * xv.z + xv.w * xv.w;
  {
    float4 w0 = reinterpret_cast<const float4*>(Wr)[d0];
    float4 w1 = reinterpret_cast<const float4*>(Wr)[d0 + 1];
    float4 w2 = reinterpret_cast<const float4*>(Wr)[d0 + 2];
    float4 w3 = reinterpret_cast<const float4*>(Wr)[d0 + 3];
    vals[2] = xv.x * w0.x + xv.y * w1.x + xv.z * w2.x + xv.w * w3.x;
    vals[3] = xv.x * w0.y + xv.y * w1.y + xv.z * w2.y + xv.w * w3.y;
    vals[4] = xv.x * w0.z + xv.y * w1.z + xv.z * w2.z + xv.w * w3.z;
    vals[5] = xv.x * w0.w + xv.y * w1.w + xv.z * w2.w + xv.w * w3.w;
  }
#pragma unroll
  for (int o = 1; o < 64; o <<= 1) {
#pragma unroll
    for (int j = 0; j < 6; j++) vals[j] += __shfl_xor(vals[j], o, 64);
  }
  __shared__ float red[4][6];
  if (lane == 0) {
#pragma unroll
    for (int j = 0; j < 6; j++) red[wave][j] = vals[j];
  }
  __syncthreads();
  float tot[6];
#pragma unroll
  for (int j = 0; j < 6; j++) tot[j] = red[0][j] + red[1][j] + red[2][j] + red[3][j];
  float mean = tot[0] * (1.0f / D_);
  float var = tot[1] * (1.0f / D_) - mean * mean;
  float rstd = rsqrtf(var + 1e-5f);
  float lg0 = tot[2] + br[0], lg1 = tot[3] + br[1], lg2 = tot[4] + br[2], lg3 = tot[5] + br[3];
  float mx = fmaxf(fmaxf(lg0, lg1), fmaxf(lg2, lg3));
  float e0 = __expf(lg0 - mx), e1 = __expf(lg1 - mx), e2 = __expf(lg2 - mx), e3 = __expf(lg3 - mx);
  float inv = 1.0f / (e0 + e1 + e2 + e3);
  float sc[4] = {e0 * inv, e1 * inv, e2 * inv, e3 * inv};
  if (t == 0) {
    float4 s4 = make_float4(sc[0], sc[1], sc[2], sc[3]);
    *reinterpret_cast<float4*>(&score_out[(long)n * 4]) = s4;
  }
  float4 hn;
  hn.x = (xv.x - mean) * rstd; hn.y = (xv.y - mean) * rstd;
  hn.z = (xv.z - mean) * rstd; hn.w = (xv.w - mean) * rstd;
#pragma unroll
  for (int e = 0; e < 4; e++) {
    float4 ge = *reinterpret_cast<const float4*>(&g[e * D_ + d0]);
    float4 be = *reinterpret_cast<const float4*>(&bb[e * D_ + d0]);
    float s = scale_flag ? sc[e] : 1.0f;
    u16x4 o;
    o[0] = f2bf((hn.x * ge.x + be.x) * s);
    o[1] = f2bf((hn.y * ge.y + be.y) * s);
    o[2] = f2bf((hn.z * ge.z + be.z) * s);
    o[3] = f2bf((hn.w * ge.w + be.w) * s);
    *reinterpret_cast<u16x4*>(&Aout[(long)e * stride_e + (long)n * stride_n + d0]) = o;
  }
}

// ======== 8-wave 256x256 GEMM, reg-double-buffered frags, 2 phases/K-tile ============
// LDS regions (u16): buf(t&1)*32768 + {A-kc0:0, A-kc1:8192, B-kc0:16384, B-kc1:24576}
// Register frag dbuf: (aC,bC)=kc0 of current tile; (aN,bN)=kc1. Each phase ds_reads the
// NEXT cluster's frags, then MFMAs the current cluster -> ds_read latency hides under MFMA.
// Phase A(t): read kc1(t)->N; GLD kc0(t+2)->buf[p]; MFMA(C); lgkm0; vmcnt; BAR
// Phase B(t): read kc0(t+1)->C (from buf[p^1]); GLD kc1(t+2)->buf[p]; MFMA(N); lgkm0; vmcnt; BAR
// Waits: A: t+1<nt ? (t+2<nt?8:4) : skip ; B: t+1<nt ? (t+2<nt?8:0) : skip.
// XCD-chunked bijective block swizzle over flat grid (totals % 8 == 0).
template <int MODE>
__global__ __launch_bounds__(512, 2) void g8(
    const u16* __restrict__ A, const u16* __restrict__ Bt, int K, int N, int kslice,
    const float* __restrict__ score, const float* __restrict__ bias,
    u16* __restrict__ outb, int eidx, long zstride) {
  __shared__ __align__(16) u16 lds0[65536];  // 128 KiB
  const int tid = threadIdx.x;
  const int w = tid >> 6, lane = tid & 63;
  const int l15 = lane & 15, l4 = lane >> 4;
  const int wr = w >> 2, wc = w & 3;

  // ---- XCD-aware swizzle ----
  const int gx = gridDim.x, gy = gridDim.y;
  const int total = gx * gy * gridDim.z;
  const int flat = blockIdx.x + gx * (blockIdx.y + gy * blockIdx.z);
  const int cpx = total >> 3;
  const int nf = (flat & 7) * cpx + (flat >> 3);
  const int bxi = nf % gx;
  const int tmp = nf / gx;
  const int byi = tmp % gy;
  const int z = tmp / gy;

  const long bm = (long)byi * 256, bn = (long)bxi * 256;
  const long k0 = (long)z * kslice;
  const int nt = kslice >> 6;

  // staging geometry
  const int cp = lane & 3;
  const int sr0 = w * 32 + (lane >> 2);
  const int sr1 = sr0 + 16;
  const int cl0 = cp ^ ((sr0 >> 1) & 3);
  const int cl1 = cp ^ ((sr1 >> 1) & 3);
  const u16* gA0 = A + (bm + sr0) * (long)K + k0 + cl0 * 8;
  const u16* gA1 = A + (bm + sr1) * (long)K + k0 + cl1 * 8;
  const u16* gB0 = Bt + (bn + sr0) * (long)K + k0 + cl0 * 8;
  const u16* gB1 = Bt + (bn + sr1) * (long)K + k0 + cl1 * 8;
  const int e0 = w * 1024;
  const int e1 = w * 1024 + 512;

  // frag-read bases (u16 units within a region)
  const int chA = l4 ^ ((l15 >> 1) & 3);
  const int rdA = (wr * 128 + l15) * 32 + chA * 8;  // + mi*512
  const int rdB = (wc * 64 + l15) * 32 + chA * 8;   // + ni*512

#define GLD(gsrc, ldsoff)                                                              \
  __builtin_amdgcn_global_load_lds(                                                    \
      (const __attribute__((address_space(1))) void*)(gsrc),                           \
      (__attribute__((address_space(3))) void*)(lds0 + (ldsoff)), 16, 0, 0)

  // -------- prologue: stage tiles 0 and 1 fully --------
  GLD(gA0, 0 + e0);
  GLD(gA1, 0 + e1);
  GLD(gB0, 16384 + e0);
  GLD(gB1, 16384 + e1);
  GLD(gA0 + 32, 8192 + e0);
  GLD(gA1 + 32, 8192 + e1);
  GLD(gB0 + 32, 24576 + e0);
  GLD(gB1 + 32, 24576 + e1);
  if (nt > 1) {
    GLD(gA0 + 64, 32768 + e0);
    GLD(gA1 + 64, 32768 + e1);
    GLD(gB0 + 64, 32768 + 16384 + e0);
    GLD(gB1 + 64, 32768 + 16384 + e1);
    GLD(gA0 + 96, 32768 + 8192 + e0);
    GLD(gA1 + 96, 32768 + 8192 + e1);
    GLD(gB0 + 96, 32768 + 24576 + e0);
    GLD(gB1 + 96, 32768 + 24576 + e1);
    asm volatile("s_waitcnt vmcnt(8)" ::: "memory");
  } else {
    asm volatile("s_waitcnt vmcnt(0)" ::: "memory");
  }
  BAR();

  f32x4 acc[8][4] = {};
  bf16x8 aC[8], bC[4], aN[8], bN[4];

  // initial frag load: kc0 of tile 0
#pragma unroll
  for (int i = 0; i < 8; i++) aC[i] = *(const bf16x8*)(lds0 + rdA + i * 512);
#pragma unroll
  for (int i = 0; i < 4; i++) bC[i] = *(const bf16x8*)(lds0 + 16384 + rdB + i * 512);

  for (int t = 0; t < nt; ++t) {
    const int base = (t & 1) * 32768;
    const int nb = base ^ 32768;
    const long ko2 = (long)(t + 2) * 64;
    // ---------- phase A: prefetch kc1(t)->N regs, stage kc0(t+2), MFMA on C ----------
#pragma unroll
    for (int i = 0; i < 8; i++) aN[i] = *(const bf16x8*)(lds0 + base + 8192 + rdA + i * 512);
#pragma unroll
    for (int i = 0; i < 4; i++) bN[i] = *(const bf16x8*)(lds0 + base + 24576 + rdB + i * 512);
    if (t + 2 < nt) {
      GLD(gA0 + ko2, base + e0);
      GLD(gA1 + ko2, base + e1);
      GLD(gB0 + ko2, base + 16384 + e0);
      GLD(gB1 + ko2, base + 16384 + e1);
    }
    __builtin_amdgcn_s_setprio(1);
#pragma unroll
    for (int mi = 0; mi < 8; mi++)
#pragma unroll
      for (int ni = 0; ni < 4; ni++)
        acc[mi][ni] = __builtin_amdgcn_mfma_f32_16x16x32_bf16(aC[mi], bC[ni], acc[mi][ni], 0, 0, 0);
    __builtin_amdgcn_s_setprio(0);
    asm volatile("s_waitcnt lgkmcnt(0)" ::: "memory");
    if (t + 1 < nt) {
      if (t + 2 < nt) {
        asm volatile("s_waitcnt vmcnt(8)" ::: "memory");
      } else {
        asm volatile("s_waitcnt vmcnt(4)" ::: "memory");
      }
    }
    BAR();
    // ---------- phase B: prefetch kc0(t+1)->C regs, stage kc1(t+2), MFMA on N ----------
    if (t + 1 < nt) {
#pragma unroll
      for (int i = 0; i < 8; i++) aC[i] = *(const bf16x8*)(lds0 + nb + rdA + i * 512);
#pragma unroll
      for (int i = 0; i < 4; i++) bC[i] = *(const bf16x8*)(lds0 + nb + 16384 + rdB + i * 512);
    }
    if (t + 2 < nt) {
      GLD(gA0 + ko2 + 32, base + 8192 + e0);
      GLD(gA1 + ko2 + 32, base + 8192 + e1);
      GLD(gB0 + ko2 + 32, base + 24576 + e0);
      GLD(gB1 + ko2 + 32, base + 24576 + e1);
    }
    __builtin_amdgcn_s_setprio(1);
#pragma unroll
    for (int mi = 0; mi < 8; mi++)
#pragma unroll
      for (int ni = 0; ni < 4; ni++)
        acc[mi][ni] = __builtin_amdgcn_mfma_f32_16x16x32_bf16(aN[mi], bN[ni], acc[mi][ni], 0, 0, 0);
    __builtin_amdgcn_s_setprio(0);
    asm volatile("s_waitcnt lgkmcnt(0)" ::: "memory");
    if (t + 1 < nt) {
      if (t + 2 < nt) {
        asm volatile("s_waitcnt vmcnt(8)" ::: "memory");
      } else {
        asm volatile("s_waitcnt vmcnt(0)" ::: "memory");
      }
    }
    BAR();
  }
#undef GLD

  // -------- epilogue --------
  const long zoff = (long)z * zstride;
#pragma unroll
  for (int ni = 0; ni < 4; ni++) {
    long col = bn + wc * 64 + ni * 16 + l15;
    float b4[4];
    float bcol = 0.0f;
    if (MODE == 0) {
#pragma unroll
      for (int e = 0; e < 4; e++) b4[e] = bias[(long)e * N + col];
    } else if (MODE == 2) {
      bcol = bias[col];
    }
#pragma unroll
    for (int mi = 0; mi < 8; mi++) {
#pragma unroll
      for (int r = 0; r < 4; r++) {
        long row = bm + wr * 128 + mi * 16 + l4 * 4 + r;
        float v = acc[mi][ni][r];
        if (MODE == 0) {
          float4 s4 = reinterpret_cast<const float4*>(score)[row];
          v += s4.x * b4[0] + s4.y * b4[1] + s4.z * b4[2] + s4.w * b4[3];
          outb[row * (long)N + col] = f2bf(v);
        } else if (MODE == 2) {
          float u = v + bcol;
          float zz = 0.7978845608f * (u + 0.044715f * u * u * u);
          float tt = __expf(2.0f * zz);
          float gel = u * (1.0f - 1.0f / (tt + 1.0f));
          outb[row * (long)N + col] = f2bf(gel * score[row * 4 + eidx]);
        } else {
          outb[zoff + row * (long)N + col] = f2bf(v);
        }
      }
    }
  }
}

// ---------------- flash attention (causal), writes A_pr = score_e * attn_out --------
__global__ __launch_bounds__(256) void attn_kernel(const u16* __restrict__ qkv,
                                                   const float* __restrict__ score_a,
                                                   u16* __restrict__ A_pr) {
  __shared__ __align__(16) u16 Kt[32 * 64];
  __shared__ __align__(16) u16 VT[64 * 32];
  __shared__ __align__(16) u16 Pl[4][16 * 32];
  int tid = threadIdx.x, wave = tid >> 6, lane = tid & 63;
  int l15 = lane & 15, l4 = lane >> 4;
  int qblk = blockIdx.x, bh = blockIdx.y;
  int b = bh >> 4, h = bh & 15;
  int q0 = qblk * 64 + wave * 16;
  const long LD = 3072;

  bf16x8 qf[2];
  {
    const u16* qp = qkv + (long)(b * 1024 + q0 + l15) * LD + h * 64 + l4 * 8;
    qf[0] = *(const bf16x8*)qp;
    qf[1] = *(const bf16x8*)(qp + 32);
  }
  f32x4 acc[4] = {};
  float m_run = -1e30f, l_run = 0.0f;
  int kv_end = qblk * 64 + 64;

  for (int kv0 = 0; kv0 < kv_end; kv0 += 32) {
    {
      int r = tid >> 3, c = (tid & 7) * 8;
      const u16* kp = qkv + (long)(b * 1024 + kv0 + r) * LD + 1024 + h * 64 + c;
      *(u16x8*)&Kt[r * 64 + c] = *(const u16x8*)kp;
      u16x8 vv = *(const u16x8*)(kp + 1024);
#pragma unroll
      for (int j = 0; j < 8; j++) VT[(c + j) * 32 + r] = vv[j];
    }
    __syncthreads();
    if (kv0 < q0 + 16) {
      float p[8];
      float pmax = -1e30f;
      int qg = q0 + l15;
#pragma unroll
      for (int ks = 0; ks < 2; ks++) {
        f32x4 st = {};
#pragma unroll
        for (int kc = 0; kc < 2; kc++) {
          bf16x8 kf = *(const bf16x8*)&Kt[(ks * 16 + l15) * 64 + kc * 32 + l4 * 8];
          st = __builtin_amdgcn_mfma_f32_16x16x32_bf16(kf, qf[kc], st, 0, 0, 0);
        }
#pragma unroll
        for (int r = 0; r < 4; r++) {
          int kvg = kv0 + ks * 16 + l4 * 4 + r;
          float v = st[r] * 0.125f;
          if (kvg > qg) v = -1e30f;
          p[ks * 4 + r] = v;
          pmax = fmaxf(pmax, v);
        }
      }
      pmax = fmaxf(pmax, __shfl_xor(pmax, 16, 64));
      pmax = fmaxf(pmax, __shfl_xor(pmax, 32, 64));
      float m_new = fmaxf(m_run, pmax);
      float alpha = __expf(m_run - m_new);
      float rsum = 0.f;
#pragma unroll
      for (int i = 0; i < 8; i++) {
        p[i] = __expf(p[i] - m_new);
        rsum += p[i];
      }
      rsum += __shfl_xor(rsum, 16, 64);
      rsum += __shfl_xor(rsum, 32, 64);
      l_run = l_run * alpha + rsum;
      m_run = m_new;
      float af4[4];
#pragma unroll
      for (int r = 0; r < 4; r++) af4[r] = __shfl(alpha, l4 * 4 + r, 64);
#pragma unroll
      for (int i = 0; i < 4; i++) {
#pragma unroll
        for (int r = 0; r < 4; r++) acc[i][r] *= af4[r];
      }
      u16* pw = &Pl[wave][0];
#pragma unroll
      for (int i = 0; i < 8; i++) {
        int ks = i >> 2, r = i & 3;
        pw[l15 * 32 + ks * 16 + l4 * 4 + r] = f2bf(p[i]);
      }
      bf16x8 pa = *(const bf16x8*)&pw[l15 * 32 + l4 * 8];
#pragma unroll
      for (int i = 0; i < 4; i++) {
        bf16x8 vf = *(const bf16x8*)&VT[(i * 16 + l15) * 32 + l4 * 8];
        acc[i] = __builtin_amdgcn_mfma_f32_16x16x32_bf16(pa, vf, acc[i], 0, 0, 0);
      }
    }
    __syncthreads();
  }

  float linv[4];
#pragma unroll
  for (int r = 0; r < 4; r++) {
    float lv = __shfl(l_run, l4 * 4 + r, 64);
    linv[r] = 1.0f / lv;
  }
#pragma unroll
  for (int r = 0; r < 4; r++) {
    int q = l4 * 4 + r;
    long nrow = (long)b * 1024 + q0 + q;
    float4 s4 = reinterpret_cast<const float4*>(score_a)[nrow];
    float se[4] = {s4.x, s4.y, s4.z, s4.w};
#pragma unroll
    for (int i = 0; i < 4; i++) {
      float v = acc[i][r] * linv[r];
      int d = h * 64 + i * 16 + l15;
#pragma unroll
      for (int e = 0; e < 4; e++) A_pr[nrow * 4096 + e * 1024 + d] = f2bf(se[e] * v);
    }
  }
}

// -------- out accumulate (vectorized x4): FIRST: out = ybuf + bias-mix + sum_z; else +=
template <int FIRST>
__global__ __launch_bounds__(256) void accum_out(const float* __restrict__ ybuf,
                                                 const float* __restrict__ score_m,
                                                 const float* __restrict__ bp2,
                                                 const u16* __restrict__ p2t,
                                                 float* __restrict__ out) {
  int n = blockIdx.x, t = threadIdx.x;
  int d0 = t * 4;
  long idx = (long)n * D_ + d0;
  float4 v;
  if (FIRST) {
    float4 s4 = reinterpret_cast<const float4*>(score_m)[n];
    float4 b0 = *reinterpret_cast<const float4*>(&bp2[d0]);
    float4 b1 = *reinterpret_cast<const float4*>(&bp2[D_ + d0]);
    float4 b2 = *reinterpret_cast<const float4*>(&bp2[2 * D_ + d0]);
    float4 b3 = *reinterpret_cast<const float4*>(&bp2[3 * D_ + d0]);
    v = *reinterpret_cast<const float4*>(&ybuf[idx]);
    v.x += s4.x * b0.x + s4.y * b1.x + s4.z * b2.x + s4.w * b3.x;
    v.y += s4.x * b0.y + s4.y * b1.y + s4.z * b2.y + s4.w * b3.y;
    v.z += s4.x * b0.z + s4.y * b1.z + s4.z * b2.z + s4.w * b3.z;
    v.w += s4.x * b0.w + s4.y * b1.w + s4.z * b2.w + s4.w * b3.w;
  } else {
    v = *reinterpret_cast<const float4*>(&out[idx]);
  }
#pragma unroll
  for (int zz = 0; zz < 4; zz++) {
    u16x4 pv = *reinterpret_cast<const u16x4*>(&p2t[(long)zz * 4194304 + idx]);
    v.x += bf2f(pv[0]); v.y += bf2f(pv[1]); v.z += bf2f(pv[2]); v.w += bf2f(pv[3]);
  }
  *reinterpret_cast<float4*>(&out[idx]) = v;
}

extern "C" void kernel_launch(void* const* d_in, const int* in_sizes, int n_in, void* d_out,
                              int out_size, void* d_ws, size_t ws_size, hipStream_t stream) {
  (void)in_sizes; (void)n_in; (void)out_size; (void)ws_size;
  const float* x    = (const float*)d_in[0];
  const float* Wr_a = (const float*)d_in[1];
  const float* br_a = (const float*)d_in[2];
  const float* g_a  = (const float*)d_in[3];
  const float* b_a  = (const float*)d_in[4];
  const float* Wqkv = (const float*)d_in[5];
  const float* bqkv = (const float*)d_in[6];
  const float* Wpr  = (const float*)d_in[7];
  const float* bpr  = (const float*)d_in[8];
  const float* Wr_m = (const float*)d_in[9];
  const float* br_m = (const float*)d_in[10];
  const float* g_m  = (const float*)d_in[11];
  const float* b_m  = (const float*)d_in[12];
  const float* Wfc  = (const float*)d_in[13];
  const float* bfc  = (const float*)d_in[14];
  const float* Wp2  = (const float*)d_in[15];
  const float* bp2  = (const float*)d_in[16];
  float* out = (float*)d_out;

  // ---- workspace: 136.25 MB, stream-ordered region reuse ----
  char* ws = (char*)d_ws;
  const size_t oW = 0;                  // 24MB: wt_qkv -> wt_pr -> {wt_fce, wt_p2e}
  const size_t oA = 25165824;           // 32MB: A_a -> prt(bf16) -> A_fc
  const size_t oQ = oA + 33554432;      // 32MB: qkvb -> p2t(bf16)
  const size_t oP = oQ + 33554432;      // 32MB: A_pr -> inter
  const size_t oY = oP + 33554432;      // 16MB: ybuf
  const size_t oS = oY + 16777216;      // scores
  u16* wt_qkv  = (u16*)(ws + oW);
  u16* wt_pr   = (u16*)(ws + oW);
  u16* wt_fce  = (u16*)(ws + oW);
  u16* wt_p2e  = (u16*)(ws + oW + (size_t)8 * 1024 * 1024);
  u16* A_a     = (u16*)(ws + oA);
  u16* prt     = (u16*)(ws + oA);
  u16* A_fc    = (u16*)(ws + oA);
  u16* qkvb    = (u16*)(ws + oQ);
  u16* p2t     = (u16*)(ws + oQ);
  u16* A_pr    = (u16*)(ws + oP);
  u16* inter   = (u16*)(ws + oP);
  float* ybuf  = (float*)(ws + oY);
  float* score_a = (float*)(ws + oS);
  float* score_m = (float*)(ws + oS + 65536);

  dim3 tb(32, 8);
  // ---- attention half ----
  tcvt<<<dim3(3072 / 32, 4096 / 32), tb, 0, stream>>>(Wqkv, wt_qkv, 4096, 3072);
  ln_router_expand<0><<<N_, 256, 0, stream>>>(x, Wr_a, br_a, g_a, b_a, score_a, A_a,
                                              (long)1024, (long)4096, 1,
                                              nullptr, nullptr, nullptr, nullptr);
  g8<0><<<dim3(3072 / 256, 4096 / 256, 1), 512, 0, stream>>>(
      A_a, wt_qkv, 4096, 3072, 4096, score_a, bqkv, qkvb, 0, 0L);
  attn_kernel<<<dim3(S_ / 64, B_ * H_), 256, 0, stream>>>(qkvb, score_a, A_pr);
  tcvt<<<dim3(1024 / 32, 4096 / 32), tb, 0, stream>>>(Wpr, wt_pr, 4096, 1024);
  g8<4><<<dim3(1024 / 256, 4096 / 256, 4), 512, 0, stream>>>(
      A_pr, wt_pr, 4096, 1024, 1024, nullptr, nullptr, prt, 0, (long)4096 * 1024);

  // ---- MLP half (ln fused with y-reconstruction) ----
  ln_router_expand<1><<<N_, 256, 0, stream>>>(x, Wr_m, br_m, g_m, b_m,
                                              score_m, A_fc, (long)N_ * 1024, (long)1024, 0,
                                              score_a, bpr, prt, ybuf);
  for (int e = 0; e < 4; e++) {
    tcvt<<<dim3(4096 / 32, 1024 / 32), tb, 0, stream>>>(
        Wfc + (size_t)e * 1024 * 4096, wt_fce, 1024, 4096);
    g8<2><<<dim3(4096 / 256, 4096 / 256, 1), 512, 0, stream>>>(
        A_fc + (size_t)e * N_ * 1024, wt_fce, 1024, 4096, 1024, score_m,
        bfc + e * 4096, inter, e, 0L);
    tcvt<<<dim3(1024 / 32, 4096 / 32), tb, 0, stream>>>(
        Wp2 + (size_t)e * 4096 * 1024, wt_p2e, 4096, 1024);
    g8<4><<<dim3(1024 / 256, 4096 / 256, 4), 512, 0, stream>>>(
        inter, wt_p2e, 4096, 1024, 1024, nullptr, nullptr, p2t, 0, (long)4096 * 1024);
    if (e == 0) {
      accum_out<1><<<N_, 256, 0, stream>>>(ybuf, score_m, bp2, p2t, out);
    } else {
      accum_out<0><<<N_, 256, 0, stream>>>(nullptr, nullptr, nullptr, p2t, out);
    }
  }
}